// Round 1
// baseline (1453.891 us; speedup 1.0000x reference)
//
#include <hip/hip_runtime.h>
#include <math.h>

#define B_ 2
#define T_ 1024
#define C_ 768
#define NH 12
#define NBR 4
#define DH_ 64
#define HT 48
#define MROWS (B_*T_)   // 2048

#define SCALE_W 1.8137993642342178f   // pi/sqrt(3)
#define ATTNSCALE_ 0.125f             // 64^-0.5

// workspace layout (float offsets)
#define OFF_B1   0
#define OFF_B2   (OFF_B1 + T_*32)
#define OFF_EWQ  (OFF_B2 + T_*32)
#define OFF_EBQ  (OFF_EWQ + 3072*768)
#define OFF_Q    (OFF_EBQ + 3072)
#define OFF_K    (OFF_Q + MROWS*3072)
#define OFF_V    (OFF_K + MROWS*768)
#define OFF_KN   (OFF_V + MROWS*768)
#define OFF_CTX  (OFF_KN + B_*NH*T_)
// total = OFF_CTX + 2*4*1024*768 = 18181120 floats ~= 72.7 MB

// ---------------------------------------------------------------------------
// Chebyshev rotation table: base1/base2[t][j], j=0..31, n_f[j]=2j+1 (exact)
__global__ void cheb_kernel(float* __restrict__ ws) {
    int t = blockIdx.x * 256 + threadIdx.x;
    if (t >= T_) return;
    float* b1 = ws + OFF_B1 + t * 32;
    float* b2 = ws + OFF_B2 + t * 32;
    float x = 2.0f * (float)t / 1023.0f - 1.0f;
    float Tp = 1.0f;   // T_{2j}
    float Tc = x;      // T_{2j+1}
    for (int j = 0; j < 32; j++) {
        float r1 = Tc;                  // T_{2j+1}
        float r2 = 2.0f * x * Tc - Tp;  // T_{2j+2}
        float nr = sqrtf(r1 * r1 + r2 * r2 + 1e-8f);
        b1[j] = r1 / nr;
        b2[j] = r2 / nr;
        Tp = r2;
        Tc = 2.0f * x * r2 - r1;        // T_{2j+3}
    }
}

// ---------------------------------------------------------------------------
// Fold M_h = I + (A - A^T) + diag(id_bias[h]) into Wq -> EWq, bq -> Ebq
__global__ __launch_bounds__(256) void prep_wq(
    const float* __restrict__ Aw, const float* __restrict__ idb,
    const float* __restrict__ Wq, const float* __restrict__ bq,
    float* __restrict__ ws) {
    __shared__ float Ms[64][64];
    int h = blockIdx.x;
    int tid = threadIdx.x;
    for (int i = tid; i < 4096; i += 256) {
        int d = i >> 6, e = i & 63;
        float v = Aw[d * 64 + e] - Aw[e * 64 + d];
        if (d == e) v += 1.0f + idb[h * 64 + d];
        Ms[d][e] = v;
    }
    __syncthreads();
    int c = blockIdx.y * 256 + tid;   // 0..767
    float wq[64];
#pragma unroll
    for (int d = 0; d < 64; d++) wq[d] = Wq[(size_t)(h * 64 + d) * 768 + c];
    float* EWq = ws + OFF_EWQ;
    for (int e = 0; e < 64; e++) {
        float acc = 0.f;
#pragma unroll
        for (int d = 0; d < 64; d++) acc += Ms[d][e] * wq[d];
        EWq[(size_t)(h * 64 + e) * 768 + c] = acc;
    }
    if (blockIdx.y == 0 && tid < 64) {
        int e = tid;
        float acc = 0.f;
        for (int d = 0; d < 64; d++) acc += Ms[d][e] * bq[h * 64 + d];
        ws[OFF_EBQ + h * 64 + e] = acc;
    }
}

// ---------------------------------------------------------------------------
// C[M=2048,N] = A[2048,768] @ W[N,768]^T + bias  (NT SGEMM, 64x64 tile, 4x4/thr)
__global__ __launch_bounds__(256) void gemm_nt(
    const float* __restrict__ A, const float* __restrict__ W,
    const float* __restrict__ bias, float* __restrict__ Cm, int N) {
    const int K = 768;
    __shared__ float As[16][68];
    __shared__ float Bs[16][68];
    int tid = threadIdx.x;
    int m0 = blockIdx.x * 64, n0 = blockIdx.y * 64;
    int row = tid >> 2;
    int col4 = (tid & 3) << 2;
    int ty = tid >> 4, tx = tid & 15;
    float acc[4][4] = {};
    for (int k0 = 0; k0 < K; k0 += 16) {
        float4 av = *(const float4*)(A + (size_t)(m0 + row) * K + k0 + col4);
        float4 wv = *(const float4*)(W + (size_t)(n0 + row) * K + k0 + col4);
        As[col4 + 0][row] = av.x; As[col4 + 1][row] = av.y;
        As[col4 + 2][row] = av.z; As[col4 + 3][row] = av.w;
        Bs[col4 + 0][row] = wv.x; Bs[col4 + 1][row] = wv.y;
        Bs[col4 + 2][row] = wv.z; Bs[col4 + 3][row] = wv.w;
        __syncthreads();
#pragma unroll
        for (int kk = 0; kk < 16; kk++) {
            float4 a = *(const float4*)&As[kk][ty << 2];
            float4 b = *(const float4*)&Bs[kk][tx << 2];
            float af[4] = {a.x, a.y, a.z, a.w};
            float bf[4] = {b.x, b.y, b.z, b.w};
#pragma unroll
            for (int i = 0; i < 4; i++)
#pragma unroll
                for (int j = 0; j < 4; j++) acc[i][j] += af[i] * bf[j];
        }
        __syncthreads();
    }
#pragma unroll
    for (int i = 0; i < 4; i++) {
        int m = m0 + (ty << 2) + i;
#pragma unroll
        for (int j = 0; j < 4; j++) {
            int n = n0 + (tx << 2) + j;
            Cm[(size_t)m * N + n] = acc[i][j] + bias[n];
        }
    }
}

// ---------------------------------------------------------------------------
// In-place rotation of per-head 64-vectors; optionally writes key norms
__global__ void rot_kernel(float* __restrict__ buf, int heads, int stride,
                           const float* __restrict__ ws, float* __restrict__ knorm) {
    int idx = blockIdx.x * 256 + threadIdx.x;
    if (idx >= MROWS * heads) return;
    int r = idx / heads;
    int hd = idx - r * heads;
    int tloc = r & (T_ - 1);
    float* p = buf + (size_t)r * stride + hd * 64;
    const float* b1 = ws + OFF_B1 + tloc * 32;
    const float* b2 = ws + OFF_B2 + tloc * 32;
    float nrm = 0.f;
#pragma unroll
    for (int i = 0; i < 8; i++) {
        float4 lo = *(const float4*)(p + i * 4);
        float4 hi = *(const float4*)(p + 32 + i * 4);
        float4 c1 = *(const float4*)(b1 + i * 4);
        float4 c2 = *(const float4*)(b2 + i * 4);
        float4 o1, o2;
        o1.x = lo.x * c1.x - hi.x * c2.x;  o2.x = lo.x * c2.x + hi.x * c1.x;
        o1.y = lo.y * c1.y - hi.y * c2.y;  o2.y = lo.y * c2.y + hi.y * c1.y;
        o1.z = lo.z * c1.z - hi.z * c2.z;  o2.z = lo.z * c2.z + hi.z * c1.z;
        o1.w = lo.w * c1.w - hi.w * c2.w;  o2.w = lo.w * c2.w + hi.w * c1.w;
        *(float4*)(p + i * 4) = o1;
        *(float4*)(p + 32 + i * 4) = o2;
        nrm += o1.x * o1.x + o1.y * o1.y + o1.z * o1.z + o1.w * o1.w;
        nrm += o2.x * o2.x + o2.y * o2.y + o2.z * o2.z + o2.w * o2.w;
    }
    if (knorm) {
        int b = r >> 10;
        knorm[((b * NH + hd) << 10) + tloc] = sqrtf(fmaxf(nrm, 1e-6f));
    }
}

// ---------------------------------------------------------------------------
// Flash-style attention: block = (b,h) x 256 t-rows; K/V tiles (64) in LDS
__global__ __launch_bounds__(256) void attn_kernel(
    const float* __restrict__ Q, const float* __restrict__ Kb,
    const float* __restrict__ Vb, const float* __restrict__ kn,
    const float* __restrict__ sinks, const float* __restrict__ vnull,
    float* __restrict__ ctx) {
    __shared__ float Ks[64][68];
    __shared__ float Vs[64][68];
    __shared__ float rks[64];
    int tid = threadIdx.x;
    int ttile = blockIdx.x;           // 0..3
    int bh = blockIdx.y;              // 0..95
    int b = bh / HT, h = bh - b * HT;
    int hk = h % NH;
    int t = ttile * 256 + tid;
    const float* qp = Q + (size_t)(b * T_ + t) * 3072 + h * 64;
    float4 q4[16];
#pragma unroll
    for (int i = 0; i < 16; i++) q4[i] = *(const float4*)(qp + i * 4);
    float4 acc[16];
#pragma unroll
    for (int i = 0; i < 16; i++) acc[i] = make_float4(0.f, 0.f, 0.f, 0.f);
    float sumw = 0.f;
    int ntiles = (ttile + 1) * 4;
    int srow = tid >> 2;
    int spart = (tid & 3) << 4;  // 0,16,32,48
    for (int st = 0; st < ntiles; st++) {
        int s0 = st * 64;
        {
            const float* kp = Kb + (size_t)(b * T_ + s0 + srow) * 768 + hk * 64 + spart;
            const float* vp = Vb + (size_t)(b * T_ + s0 + srow) * 768 + hk * 64 + spart;
#pragma unroll
            for (int u = 0; u < 4; u++) {
                float4 kv = *(const float4*)(kp + u * 4);
                float4 vv = *(const float4*)(vp + u * 4);
                *(float4*)&Ks[srow][spart + u * 4] = kv;
                *(float4*)&Vs[srow][spart + u * 4] = vv;
            }
            if (tid < 64) rks[tid] = ATTNSCALE_ / kn[((b * NH + hk) << 10) + s0 + tid];
        }
        __syncthreads();
        int smax = t - s0; if (smax > 63) smax = 63;
        for (int ss = 0; ss <= smax; ss++) {
            const float4* kr = (const float4*)&Ks[ss][0];
            float dx = 0.f, dy = 0.f, dz = 0.f, dw = 0.f;
#pragma unroll
            for (int i = 0; i < 16; i++) {
                float4 k4 = kr[i];
                dx += q4[i].x * k4.x; dy += q4[i].y * k4.y;
                dz += q4[i].z * k4.z; dw += q4[i].w * k4.w;
            }
            float x = (dx + dy + dz + dw) * rks[ss];
            float w = __logf(1.f + __expf(x));                       // softplus
            float sg = 1.f + __expf(-SCALE_W * w);
            w = w * __builtin_amdgcn_rcpf(sg);                       // swish gate
            sumw += w;
            const float4* vr = (const float4*)&Vs[ss][0];
#pragma unroll
            for (int i = 0; i < 16; i++) {
                float4 v4 = vr[i];
                acc[i].x += w * v4.x; acc[i].y += w * v4.y;
                acc[i].z += w * v4.z; acc[i].w += w * v4.w;
            }
        }
        __syncthreads();
    }
    float skv = sinks[h];
    float alpha = 1.0f / (sumw + skv + 1e-6f);
    float ps = skv * alpha;
    int nb = h / NH;
    float* cp = ctx + ((size_t)((b * NBR + nb) * T_ + t)) * 768 + hk * 64;
    const float* vn = vnull + h * 64;
#pragma unroll
    for (int i = 0; i < 16; i++) {
        float4 v4 = *(const float4*)(vn + i * 4);
        float4 o;
        o.x = acc[i].x * alpha + ps * v4.x;
        o.y = acc[i].y * alpha + ps * v4.y;
        o.z = acc[i].z * alpha + ps * v4.z;
        o.w = acc[i].w * alpha + ps * v4.w;
        *(float4*)(cp + i * 4) = o;
    }
}

// ---------------------------------------------------------------------------
// Y[m,c] = 0.25 * sum_nb ( ctx[nb] @ Wo[nb] )[m,c] + 0.25*sum_nb bo[nb,c]
__global__ __launch_bounds__(256) void gemm_out(
    const float* __restrict__ ctx, const float* __restrict__ Wo,
    const float* __restrict__ bo, float* __restrict__ Y) {
    __shared__ float As[16][68];
    __shared__ float Bs[16][68];
    int tid = threadIdx.x;
    int m0 = blockIdx.x * 64, n0 = blockIdx.y * 64;
    int b = m0 >> 10; int t0 = m0 & 1023;
    int row = tid >> 2, col4 = (tid & 3) << 2;
    int rB = tid >> 4, cB = (tid & 15) << 2;
    int ty = tid >> 4, tx = tid & 15;
    float acc[4][4] = {};
    for (int nb = 0; nb < 4; nb++) {
        const float* Ab = ctx + ((size_t)((b * NBR + nb) * T_ + t0)) * 768;
        const float* Wb = Wo + (size_t)nb * 768 * 768;
        for (int k0 = 0; k0 < 768; k0 += 16) {
            float4 av = *(const float4*)(Ab + (size_t)row * 768 + k0 + col4);
            As[col4 + 0][row] = av.x; As[col4 + 1][row] = av.y;
            As[col4 + 2][row] = av.z; As[col4 + 3][row] = av.w;
            float4 wv = *(const float4*)(Wb + (size_t)(k0 + rB) * 768 + n0 + cB);
            *(float4*)&Bs[rB][cB] = wv;
            __syncthreads();
#pragma unroll
            for (int kk = 0; kk < 16; kk++) {
                float4 a = *(const float4*)&As[kk][ty << 2];
                float4 bb = *(const float4*)&Bs[kk][tx << 2];
                float af[4] = {a.x, a.y, a.z, a.w};
                float bf[4] = {bb.x, bb.y, bb.z, bb.w};
#pragma unroll
                for (int i = 0; i < 4; i++)
#pragma unroll
                    for (int j = 0; j < 4; j++) acc[i][j] += af[i] * bf[j];
            }
            __syncthreads();
        }
    }
#pragma unroll
    for (int j = 0; j < 4; j++) {
        int n = n0 + (tx << 2) + j;
        float bsum = 0.25f * (bo[n] + bo[768 + n] + bo[1536 + n] + bo[2304 + n]);
#pragma unroll
        for (int i = 0; i < 4; i++) {
            int m = m0 + (ty << 2) + i;
            Y[(size_t)m * 768 + n] = 0.25f * acc[i][j] + bsum;
        }
    }
}

// ---------------------------------------------------------------------------
extern "C" void kernel_launch(void* const* d_in, const int* in_sizes, int n_in,
                              void* d_out, int out_size, void* d_ws, size_t ws_size,
                              hipStream_t stream) {
    const float* X   = (const float*)d_in[0];
    const float* Wq  = (const float*)d_in[1];
    const float* bq  = (const float*)d_in[2];
    const float* Wk  = (const float*)d_in[3];
    const float* bk  = (const float*)d_in[4];
    const float* Wv  = (const float*)d_in[5];
    const float* bv  = (const float*)d_in[6];
    const float* Aw  = (const float*)d_in[7];
    const float* idb = (const float*)d_in[8];
    const float* sk  = (const float*)d_in[9];
    const float* vn  = (const float*)d_in[10];
    const float* Wo  = (const float*)d_in[11];
    const float* bo  = (const float*)d_in[12];
    float* ws = (float*)d_ws;
    float* Y  = (float*)d_out;

    hipLaunchKernelGGL(cheb_kernel, dim3(4), dim3(256), 0, stream, ws);
    hipLaunchKernelGGL(prep_wq, dim3(48, 3), dim3(256), 0, stream, Aw, idb, Wq, bq, ws);
    // Q = X @ EWq^T + Ebq   (2048 x 3072)
    hipLaunchKernelGGL(gemm_nt, dim3(32, 48), dim3(256), 0, stream,
                       X, ws + OFF_EWQ, ws + OFF_EBQ, ws + OFF_Q, 3072);
    // K = X @ Wk^T + bk     (2048 x 768)
    hipLaunchKernelGGL(gemm_nt, dim3(32, 12), dim3(256), 0, stream,
                       X, Wk, bk, ws + OFF_K, 768);
    // V = X @ Wv^T + bv     (2048 x 768)
    hipLaunchKernelGGL(gemm_nt, dim3(32, 12), dim3(256), 0, stream,
                       X, Wv, bv, ws + OFF_V, 768);
    // rotate Q (48 heads/row), K (12 heads/row, + key norms)
    hipLaunchKernelGGL(rot_kernel, dim3(384), dim3(256), 0, stream,
                       ws + OFF_Q, 48, 3072, ws, (float*)nullptr);
    hipLaunchKernelGGL(rot_kernel, dim3(96), dim3(256), 0, stream,
                       ws + OFF_K, 12, 768, ws, ws + OFF_KN);
    // attention -> ctx (B,4,T,768)
    hipLaunchKernelGGL(attn_kernel, dim3(4, 96), dim3(256), 0, stream,
                       ws + OFF_Q, ws + OFF_K, ws + OFF_V, ws + OFF_KN, sk, vn,
                       ws + OFF_CTX);
    // output projection + branch mean
    hipLaunchKernelGGL(gemm_out, dim3(32, 12), dim3(256), 0, stream,
                       ws + OFF_CTX, Wo, bo, Y);
}

// Round 2
// 671.021 us; speedup vs baseline: 2.1667x; 2.1667x over previous
//
#include <hip/hip_runtime.h>
#include <math.h>

#define B_ 2
#define T_ 1024
#define C_ 768
#define NH 12
#define NBR 4
#define DH_ 64
#define HT 48
#define MROWS (B_*T_)   // 2048

#define SCALE_W 1.8137993642342178f   // pi/sqrt(3)
#define ATTNSCALE_ 0.125f             // 64^-0.5

// ---------------- workspace layout (float offsets) -------------------------
#define OFF_B1   0
#define OFF_B2   (OFF_B1 + T_*32)                    // 32768
#define OFF_EWQ  (OFF_B2 + T_*32)                    // 65536
#define OFF_EBQ  (OFF_EWQ + 3072*768)                // 2424832
#define OFF_QF   (OFF_EBQ + 3072)                    // 2427904  fp32 Q (2048x3072)
#define OFF_KF   (OFF_QF + MROWS*3072)               // 8719360  fp32 K (2048x768)
#define OFF_VF   (OFF_KF + MROWS*768)                // 10292224 fp32 V
// bf16 Q aliases the (dead-by-then) fp32 K+V region: exactly 3145728 floats
#define OFF_QB   OFF_KF                              // ushort[2*48*1024*64]
#define OFF_KB   (OFF_VF + MROWS*768)                // 11865088 ushort[2*12*1024*64]
#define OFF_VB   (OFF_KB + MROWS*384)                // 12651520
#define OFF_RKS  (OFF_VB + MROWS*384)                // 13437952 float[2*12*1024]
// fp32 ctx aliases the (dead-by-then) fp32 Q region
#define OFF_CTX  OFF_QF
// total ws use = 13462528 floats = 53.9 MB

typedef __attribute__((ext_vector_type(8))) short short8t;
typedef __attribute__((ext_vector_type(4))) float f32x4;

__device__ inline ushort f2bf(float f) {
    union { float f; unsigned u; } v; v.f = f;
    unsigned r = (v.u + 0x7FFFu + ((v.u >> 16) & 1u)) >> 16;
    return (ushort)r;
}

// ---------------------------------------------------------------------------
// Chebyshev rotation table: base1/base2[t][j], j=0..31, n_f[j]=2j+1 (exact)
__global__ void cheb_kernel(float* __restrict__ ws) {
    int t = blockIdx.x * 256 + threadIdx.x;
    if (t >= T_) return;
    float* b1 = ws + OFF_B1 + t * 32;
    float* b2 = ws + OFF_B2 + t * 32;
    float x = 2.0f * (float)t / 1023.0f - 1.0f;
    float Tp = 1.0f, Tc = x;
    for (int j = 0; j < 32; j++) {
        float r1 = Tc;
        float r2 = 2.0f * x * Tc - Tp;
        float nr = sqrtf(r1 * r1 + r2 * r2 + 1e-8f);
        b1[j] = r1 / nr;
        b2[j] = r2 / nr;
        Tp = r2;
        Tc = 2.0f * x * r2 - r1;
    }
}

// ---------------------------------------------------------------------------
// Fold M_h = I + (A - A^T) + diag(id_bias[h]) into Wq -> EWq, bq -> Ebq
__global__ __launch_bounds__(256) void prep_wq(
    const float* __restrict__ Aw, const float* __restrict__ idb,
    const float* __restrict__ Wq, const float* __restrict__ bq,
    float* __restrict__ ws) {
    __shared__ float Ms[64][64];
    int h = blockIdx.x;
    int tid = threadIdx.x;
    for (int i = tid; i < 4096; i += 256) {
        int d = i >> 6, e = i & 63;
        float v = Aw[d * 64 + e] - Aw[e * 64 + d];
        if (d == e) v += 1.0f + idb[h * 64 + d];
        Ms[d][e] = v;
    }
    __syncthreads();
    int c = blockIdx.y * 256 + tid;
    float wq[64];
#pragma unroll
    for (int d = 0; d < 64; d++) wq[d] = Wq[(size_t)(h * 64 + d) * 768 + c];
    float* EWq = ws + OFF_EWQ;
    for (int e = 0; e < 64; e++) {
        float acc = 0.f;
#pragma unroll
        for (int d = 0; d < 64; d++) acc += Ms[d][e] * wq[d];
        EWq[(size_t)(h * 64 + e) * 768 + c] = acc;
    }
    if (blockIdx.y == 0 && tid < 64) {
        int e = tid;
        float acc = 0.f;
        for (int d = 0; d < 64; d++) acc += Ms[d][e] * bq[h * 64 + d];
        ws[OFF_EBQ + h * 64 + e] = acc;
    }
}

// ---------------------------------------------------------------------------
// C[M=2048,N] = A[2048,768] @ W[N,768]^T + bias  (NT SGEMM, 64x64 tile)
__global__ __launch_bounds__(256) void gemm_nt(
    const float* __restrict__ A, const float* __restrict__ W,
    const float* __restrict__ bias, float* __restrict__ Cm, int N) {
    const int K = 768;
    __shared__ float As[16][68];
    __shared__ float Bs[16][68];
    int tid = threadIdx.x;
    int m0 = blockIdx.x * 64, n0 = blockIdx.y * 64;
    int row = tid >> 2;
    int col4 = (tid & 3) << 2;
    int ty = tid >> 4, tx = tid & 15;
    float acc[4][4] = {};
    for (int k0 = 0; k0 < K; k0 += 16) {
        float4 av = *(const float4*)(A + (size_t)(m0 + row) * K + k0 + col4);
        float4 wv = *(const float4*)(W + (size_t)(n0 + row) * K + k0 + col4);
        As[col4 + 0][row] = av.x; As[col4 + 1][row] = av.y;
        As[col4 + 2][row] = av.z; As[col4 + 3][row] = av.w;
        Bs[col4 + 0][row] = wv.x; Bs[col4 + 1][row] = wv.y;
        Bs[col4 + 2][row] = wv.z; Bs[col4 + 3][row] = wv.w;
        __syncthreads();
#pragma unroll
        for (int kk = 0; kk < 16; kk++) {
            float4 a = *(const float4*)&As[kk][ty << 2];
            float4 b = *(const float4*)&Bs[kk][tx << 2];
            float af[4] = {a.x, a.y, a.z, a.w};
            float bf[4] = {b.x, b.y, b.z, b.w};
#pragma unroll
            for (int i = 0; i < 4; i++)
#pragma unroll
                for (int j = 0; j < 4; j++) acc[i][j] += af[i] * bf[j];
        }
        __syncthreads();
    }
#pragma unroll
    for (int i = 0; i < 4; i++) {
        int m = m0 + (ty << 2) + i;
#pragma unroll
        for (int j = 0; j < 4; j++) {
            int n = n0 + (tx << 2) + j;
            Cm[(size_t)m * N + n] = acc[i][j] + bias[n];
        }
    }
}

// ---------------------------------------------------------------------------
// Rotate per-head 64-vectors, emit head-major bf16; optional rks = 0.125/|k|
__global__ void rot2_kernel(const float* __restrict__ in, int heads,
                            ushort* __restrict__ outb, float* __restrict__ rkso,
                            const float* __restrict__ ws) {
    int idx = blockIdx.x * 256 + threadIdx.x;
    if (idx >= MROWS * heads) return;
    int r = idx / heads;
    int hd = idx - r * heads;
    int tloc = r & (T_ - 1);
    int b = r >> 10;
    const float* p = in + (size_t)r * (heads * 64) + hd * 64;
    const float* b1 = ws + OFF_B1 + tloc * 32;
    const float* b2 = ws + OFF_B2 + tloc * 32;
    __align__(16) ushort ob[64];
    float nrm = 0.f;
#pragma unroll
    for (int i = 0; i < 8; i++) {
        float4 lo = *(const float4*)(p + i * 4);
        float4 hi = *(const float4*)(p + 32 + i * 4);
        float4 c1 = *(const float4*)(b1 + i * 4);
        float4 c2 = *(const float4*)(b2 + i * 4);
        float o1[4], o2[4];
        o1[0] = lo.x * c1.x - hi.x * c2.x;  o2[0] = lo.x * c2.x + hi.x * c1.x;
        o1[1] = lo.y * c1.y - hi.y * c2.y;  o2[1] = lo.y * c2.y + hi.y * c1.y;
        o1[2] = lo.z * c1.z - hi.z * c2.z;  o2[2] = lo.z * c2.z + hi.z * c1.z;
        o1[3] = lo.w * c1.w - hi.w * c2.w;  o2[3] = lo.w * c2.w + hi.w * c1.w;
#pragma unroll
        for (int j = 0; j < 4; j++) {
            ob[i * 4 + j]      = f2bf(o1[j]);
            ob[32 + i * 4 + j] = f2bf(o2[j]);
            nrm += o1[j] * o1[j] + o2[j] * o2[j];
        }
    }
    ushort* op = outb + ((size_t)(b * heads + hd) * T_ + tloc) * 64;
#pragma unroll
    for (int i = 0; i < 8; i++) *(int4*)(op + i * 8) = *(const int4*)&ob[i * 8];
    if (rkso) rkso[((b * heads + hd) << 10) + tloc] = ATTNSCALE_ / sqrtf(fmaxf(nrm, 1e-6f));
}

// ---------------------------------------------------------------------------
// Convert fp32 V [2048][768] -> head-major bf16 [b][12][1024][64]
__global__ void vconv_kernel(const float* __restrict__ V, ushort* __restrict__ Vb) {
    int idx = blockIdx.x * 256 + threadIdx.x;   // x4 elements
    int base = idx * 4;
    int row = base / 768, col = base - row * 768;
    int b = row >> 10, t = row & (T_ - 1);
    int hk = col >> 6, d = col & 63;
    float4 v = *(const float4*)(V + (size_t)row * 768 + col);
    ushort4 o;
    o.x = f2bf(v.x); o.y = f2bf(v.y); o.z = f2bf(v.z); o.w = f2bf(v.w);
    *(ushort4*)(Vb + ((size_t)((b * NH + hk) * T_ + t)) * 64 + d) = o;
}

// ---------------------------------------------------------------------------
// MFMA flash attention: block = 64 q-rows x one (b,h); 4 waves x 16 rows each
__global__ __launch_bounds__(256) void attn_mfma(
    const ushort* __restrict__ Qb, const ushort* __restrict__ Kb,
    const ushort* __restrict__ Vb, const float* __restrict__ rks,
    const float* __restrict__ sinks, const float* __restrict__ vnull,
    float* __restrict__ ctx) {
    __shared__ __align__(16) ushort Ks[64][72];
    __shared__ __align__(16) ushort Vt[64][72];
    __shared__ __align__(16) ushort Ps[4][16][72];
    __shared__ float rk_s[64];
    int tid  = threadIdx.x;
    int lane = tid & 63;
    int wid  = tid >> 6;
    int qi = 15 - blockIdx.x;        // deepest blocks first (load balance)
    int bh = blockIdx.y;
    int b = bh / HT, h = bh - b * HT;
    int hk = h % NH;
    int qt0 = qi * 64;
    int g = lane >> 4;               // 0..3
    int c = lane & 15;               // 0..15

    // Q A-fragments (consistent k-mapping: k = hf*32 + g*8 + j)
    const ushort* qrow = Qb + ((size_t)(b * HT + h) * T_ + qt0 + wid * 16 + c) * 64;
    short8t qa0 = *(const short8t*)(qrow + g * 8);
    short8t qa1 = *(const short8t*)(qrow + 32 + g * 8);

    f32x4 oacc[4] = {};
    float sumw[4] = {0.f, 0.f, 0.f, 0.f};

    const size_t kvbase = (size_t)(b * NH + hk) * T_;
    for (int st = 0; st <= qi; st++) {
        int s0 = st * 64;
        __syncthreads();
        {   // stage K tile + transposed V tile + rks
            int r = tid >> 2, c0 = (tid & 3) * 16;
            const ushort* kp = Kb + (kvbase + s0 + r) * 64 + c0;
            *(int4*)&Ks[r][c0]     = *(const int4*)kp;
            *(int4*)&Ks[r][c0 + 8] = *(const int4*)(kp + 8);
            const ushort* vp = Vb + (kvbase + s0 + r) * 64 + c0;
            __align__(16) ushort vv[16];
            *(int4*)&vv[0] = *(const int4*)vp;
            *(int4*)&vv[8] = *(const int4*)(vp + 8);
#pragma unroll
            for (int j = 0; j < 16; j++) Vt[c0 + j][r] = vv[j];
            if (tid < 64) rk_s[tid] = rks[(kvbase << 0) + ((size_t)s0 + tid)];
        }
        __syncthreads();

        // S = Q @ K^T  (per wave: 16 rows x 64 s-cols)
        f32x4 sfr[4];
#pragma unroll
        for (int f = 0; f < 4; f++) {
            f32x4 cacc = {0.f, 0.f, 0.f, 0.f};
            short8t kb0 = *(const short8t*)&Ks[f * 16 + c][g * 8];
            cacc = __builtin_amdgcn_mfma_f32_16x16x32_bf16(qa0, kb0, cacc, 0, 0, 0);
            short8t kb1 = *(const short8t*)&Ks[f * 16 + c][32 + g * 8];
            cacc = __builtin_amdgcn_mfma_f32_16x16x32_bf16(qa1, kb1, cacc, 0, 0, 0);
            sfr[f] = cacc;
        }

        // nonlinearity + causal mask + P -> LDS (bf16)
        bool diag = (st == qi);
#pragma unroll
        for (int f = 0; f < 4; f++) {
            int scol = f * 16 + c;
            float rkv = rk_s[scol];
#pragma unroll
            for (int r = 0; r < 4; r++) {
                int trow = g * 4 + r;
                float x = sfr[f][r] * rkv;
                float w = __logf(1.f + __expf(x));
                w = w * __builtin_amdgcn_rcpf(1.f + __expf(-SCALE_W * w));
                if (diag && scol > wid * 16 + trow) w = 0.f;
                sumw[r] += w;
                Ps[wid][trow][scol] = f2bf(w);
            }
        }

        // O += P @ V  (per wave: 16 rows x 64 d-cols)
#pragma unroll
        for (int hf = 0; hf < 2; hf++) {
            short8t pa = *(const short8t*)&Ps[wid][c][hf * 32 + g * 8];
#pragma unroll
            for (int f = 0; f < 4; f++) {
                short8t vb = *(const short8t*)&Vt[f * 16 + c][hf * 32 + g * 8];
                oacc[f] = __builtin_amdgcn_mfma_f32_16x16x32_bf16(pa, vb, oacc[f], 0, 0, 0);
            }
        }
    }

    // row sums live split across the 16 lanes of each g-group: reduce
#pragma unroll
    for (int m = 1; m < 16; m <<= 1) {
#pragma unroll
        for (int r = 0; r < 4; r++) sumw[r] += __shfl_xor(sumw[r], m, 64);
    }
    float skv = sinks[h];
    float alpha[4], ps[4];
#pragma unroll
    for (int r = 0; r < 4; r++) {
        alpha[r] = 1.0f / (sumw[r] + skv + 1e-6f);
        ps[r] = skv * alpha[r];
    }
    int nb = h / NH;
#pragma unroll
    for (int f = 0; f < 4; f++) {
        float vn = vnull[h * 64 + f * 16 + c];
#pragma unroll
        for (int r = 0; r < 4; r++) {
            int t = qt0 + wid * 16 + g * 4 + r;
            ctx[((size_t)((b * NBR + nb) * T_ + t)) * 768 + hk * 64 + f * 16 + c]
                = oacc[f][r] * alpha[r] + ps[r] * vn;
        }
    }
}

// ---------------------------------------------------------------------------
// Y[m,c] = 0.25 * sum_nb ( ctx[nb] @ Wo[nb] )[m,c] + 0.25*sum_nb bo[nb,c]
__global__ __launch_bounds__(256) void gemm_out(
    const float* __restrict__ ctx, const float* __restrict__ Wo,
    const float* __restrict__ bo, float* __restrict__ Y) {
    __shared__ float As[16][68];
    __shared__ float Bs[16][68];
    int tid = threadIdx.x;
    int m0 = blockIdx.x * 64, n0 = blockIdx.y * 64;
    int b = m0 >> 10; int t0 = m0 & 1023;
    int row = tid >> 2, col4 = (tid & 3) << 2;
    int rB = tid >> 4, cB = (tid & 15) << 2;
    int ty = tid >> 4, tx = tid & 15;
    float acc[4][4] = {};
    for (int nb = 0; nb < 4; nb++) {
        const float* Ab = ctx + ((size_t)((b * NBR + nb) * T_ + t0)) * 768;
        const float* Wb = Wo + (size_t)nb * 768 * 768;
        for (int k0 = 0; k0 < 768; k0 += 16) {
            float4 av = *(const float4*)(Ab + (size_t)row * 768 + k0 + col4);
            As[col4 + 0][row] = av.x; As[col4 + 1][row] = av.y;
            As[col4 + 2][row] = av.z; As[col4 + 3][row] = av.w;
            float4 wv = *(const float4*)(Wb + (size_t)(k0 + rB) * 768 + n0 + cB);
            *(float4*)&Bs[rB][cB] = wv;
            __syncthreads();
#pragma unroll
            for (int kk = 0; kk < 16; kk++) {
                float4 a = *(const float4*)&As[kk][ty << 2];
                float4 bb = *(const float4*)&Bs[kk][tx << 2];
                float af[4] = {a.x, a.y, a.z, a.w};
                float bf[4] = {bb.x, bb.y, bb.z, bb.w};
#pragma unroll
                for (int i = 0; i < 4; i++)
#pragma unroll
                    for (int j = 0; j < 4; j++) acc[i][j] += af[i] * bf[j];
            }
            __syncthreads();
        }
    }
#pragma unroll
    for (int j = 0; j < 4; j++) {
        int n = n0 + (tx << 2) + j;
        float bsum = 0.25f * (bo[n] + bo[768 + n] + bo[1536 + n] + bo[2304 + n]);
#pragma unroll
        for (int i = 0; i < 4; i++) {
            int m = m0 + (ty << 2) + i;
            Y[(size_t)m * 768 + n] = 0.25f * acc[i][j] + bsum;
        }
    }
}

// ---------------------------------------------------------------------------
extern "C" void kernel_launch(void* const* d_in, const int* in_sizes, int n_in,
                              void* d_out, int out_size, void* d_ws, size_t ws_size,
                              hipStream_t stream) {
    const float* X   = (const float*)d_in[0];
    const float* Wq  = (const float*)d_in[1];
    const float* bq  = (const float*)d_in[2];
    const float* Wk  = (const float*)d_in[3];
    const float* bk  = (const float*)d_in[4];
    const float* Wv  = (const float*)d_in[5];
    const float* bv  = (const float*)d_in[6];
    const float* Aw  = (const float*)d_in[7];
    const float* idb = (const float*)d_in[8];
    const float* sk  = (const float*)d_in[9];
    const float* vn  = (const float*)d_in[10];
    const float* Wo  = (const float*)d_in[11];
    const float* bo  = (const float*)d_in[12];
    float* ws = (float*)d_ws;
    float* Y  = (float*)d_out;

    hipLaunchKernelGGL(cheb_kernel, dim3(4), dim3(256), 0, stream, ws);
    hipLaunchKernelGGL(prep_wq, dim3(48, 3), dim3(256), 0, stream, Aw, idb, Wq, bq, ws);
    // fp32 projections
    hipLaunchKernelGGL(gemm_nt, dim3(32, 48), dim3(256), 0, stream,
                       X, ws + OFF_EWQ, ws + OFF_EBQ, ws + OFF_QF, 3072);
    hipLaunchKernelGGL(gemm_nt, dim3(32, 12), dim3(256), 0, stream,
                       X, Wk, bk, ws + OFF_KF, 768);
    hipLaunchKernelGGL(gemm_nt, dim3(32, 12), dim3(256), 0, stream,
                       X, Wv, bv, ws + OFF_VF, 768);
    // K: rotate -> bf16 head-major + rks   (must run before QB overwrites KF/VF)
    hipLaunchKernelGGL(rot2_kernel, dim3(96), dim3(256), 0, stream,
                       ws + OFF_KF, NH, (ushort*)(ws + OFF_KB), ws + OFF_RKS, ws);
    // V: convert -> bf16 head-major
    hipLaunchKernelGGL(vconv_kernel, dim3(1536), dim3(256), 0, stream,
                       ws + OFF_VF, (ushort*)(ws + OFF_VB));
    // Q: rotate -> bf16 head-major (writes over dead fp32 K/V region)
    hipLaunchKernelGGL(rot2_kernel, dim3(384), dim3(256), 0, stream,
                       ws + OFF_QF, HT, (ushort*)(ws + OFF_QB), (float*)nullptr, ws);
    // MFMA flash attention -> ctx (over dead fp32 Q region)
    hipLaunchKernelGGL(attn_mfma, dim3(16, 96), dim3(256), 0, stream,
                       (const ushort*)(ws + OFF_QB), (const ushort*)(ws + OFF_KB),
                       (const ushort*)(ws + OFF_VB), ws + OFF_RKS, sk, vn,
                       ws + OFF_CTX);
    // output projection + branch mean
    hipLaunchKernelGGL(gemm_out, dim3(32, 12), dim3(256), 0, stream,
                       ws + OFF_CTX, Wo, bo, Y);
}

// Round 4
// 490.512 us; speedup vs baseline: 2.9640x; 1.3680x over previous
//
#include <hip/hip_runtime.h>
#include <math.h>

#define B_ 2
#define T_ 1024
#define C_ 768
#define NH 12
#define NBR 4
#define DH_ 64
#define HT 48
#define MROWS (B_*T_)   // 2048

#define SCALE_W 1.8137993642342178f   // pi/sqrt(3)
#define ATTNSCALE_ 0.125f             // 64^-0.5

// ---------------- workspace layout (float offsets) -------------------------
#define OFF_B1    0
#define OFF_B2    (OFF_B1 + T_*32)            // 32768
#define OFF_EWQ   (OFF_B2 + T_*32)            // 65536    fp32[3072*768]
#define OFF_EBQ   (OFF_EWQ + 2359296)         // 2424832  fp32[3072]
#define OFF_XB    (OFF_EBQ + 3072)            // 2427904  ushort[2048*768]  (786432 fl)
#define OFF_WKB   (OFF_XB + 786432)           // 3214336  ushort[768*768]   (294912 fl)
#define OFF_WVB   (OFF_WKB + 294912)          // 3509248  ushort[768*768]
#define OFF_EWQB  (OFF_WVB + 294912)          // 3804160  ushort[3072*768]  (1179648 fl)
#define OFF_QF    (OFF_EWQB + 1179648)        // 4983808  fp32[2048*3072]
#define OFF_KF    (OFF_QF + MROWS*3072)       // 11275264 fp32[2048*768]
#define OFF_VF    (OFF_KF + MROWS*768)        // 12848128 fp32[2048*768]
// bf16 Q aliases dead fp32 K+V (needs 3145728 fl = KF+VF exactly)
#define OFF_QB    OFF_KF
#define OFF_KB    (OFF_VF + MROWS*768)        // 14420992 ushort[2*12*1024*64] (786432 fl)
#define OFF_VB    (OFF_KB + MROWS*384)        // 15207424
#define OFF_RKS   (OFF_VB + MROWS*384)        // 15993856 fp32[2*12*1024]
// fp32 ctx aliases dead fp32 Q (6291456 fl, exact fit)
#define OFF_CTX   OFF_QF
// end = 16018432 floats = 64.1 MB (ws >= 72.7 MB proven in round 1)

typedef __attribute__((ext_vector_type(8))) short short8t;
typedef __attribute__((ext_vector_type(4))) float f32x4;

__device__ inline ushort f2bf(float f) {
    union { float f; unsigned u; } v; v.f = f;
    unsigned r = (v.u + 0x7FFFu + ((v.u >> 16) & 1u)) >> 16;
    return (ushort)r;
}

// ---------------------------------------------------------------------------
// Chebyshev rotation table: base1/base2[t][j], j=0..31, n_f[j]=2j+1 (exact)
__global__ void cheb_kernel(float* __restrict__ ws) {
    int t = blockIdx.x * 256 + threadIdx.x;
    if (t >= T_) return;
    float* b1 = ws + OFF_B1 + t * 32;
    float* b2 = ws + OFF_B2 + t * 32;
    float x = 2.0f * (float)t / 1023.0f - 1.0f;
    float Tp = 1.0f, Tc = x;
    for (int j = 0; j < 32; j++) {
        float r1 = Tc;
        float r2 = 2.0f * x * Tc - Tp;
        float nr = sqrtf(r1 * r1 + r2 * r2 + 1e-8f);
        b1[j] = r1 / nr;
        b2[j] = r2 / nr;
        Tp = r2;
        Tc = 2.0f * x * r2 - r1;
    }
}

// ---------------------------------------------------------------------------
// Fold M_h = I + (A - A^T) + diag(id_bias[h]) into Wq -> EWq (fp32), bq -> Ebq
__global__ __launch_bounds__(256) void prep_wq(
    const float* __restrict__ Aw, const float* __restrict__ idb,
    const float* __restrict__ Wq, const float* __restrict__ bq,
    float* __restrict__ ws) {
    __shared__ float Ms[64][64];
    int h = blockIdx.x;
    int tid = threadIdx.x;
    for (int i = tid; i < 4096; i += 256) {
        int d = i >> 6, e = i & 63;
        float v = Aw[d * 64 + e] - Aw[e * 64 + d];
        if (d == e) v += 1.0f + idb[h * 64 + d];
        Ms[d][e] = v;
    }
    __syncthreads();
    int c = blockIdx.y * 256 + tid;
    float wq[64];
#pragma unroll
    for (int d = 0; d < 64; d++) wq[d] = Wq[(size_t)(h * 64 + d) * 768 + c];
    float* EWq = ws + OFF_EWQ;
    for (int e = 0; e < 64; e++) {
        float acc = 0.f;
#pragma unroll
        for (int d = 0; d < 64; d++) acc += Ms[d][e] * wq[d];
        EWq[(size_t)(h * 64 + e) * 768 + c] = acc;
    }
    if (blockIdx.y == 0 && tid < 64) {
        int e = tid;
        float acc = 0.f;
        for (int d = 0; d < 64; d++) acc += Ms[d][e] * bq[h * 64 + d];
        ws[OFF_EBQ + h * 64 + e] = acc;
    }
}

// ---------------------------------------------------------------------------
// Elementwise fp32 -> bf16 (one float4 per thread)
__global__ void conv_bf16(const float* __restrict__ src, ushort* __restrict__ dst) {
    int i = (blockIdx.x * 256 + threadIdx.x) * 4;
    float4 v = *(const float4*)(src + i);
    ushort4 o;
    o.x = f2bf(v.x); o.y = f2bf(v.y); o.z = f2bf(v.z); o.w = f2bf(v.w);
    *(ushort4*)(dst + i) = o;
}

// ---------------------------------------------------------------------------
// C[M,N] = scale*(A @ B^T) + bias   A[M][K],B[N][K] bf16, C fp32
// 128x128 tile, BK=64, 4 waves (2x2), each 64x64 via 4x4 16x16x32 fragments
__global__ __launch_bounds__(256) void gemm_bf16(
    const ushort* __restrict__ A, const ushort* __restrict__ B,
    const float* __restrict__ bias, float* __restrict__ C,
    int N, int K, float scale) {
    __shared__ __align__(16) ushort As[128][72];
    __shared__ __align__(16) ushort Bs[128][72];
    int tid = threadIdx.x;
    int lane = tid & 63, wid = tid >> 6;
    int wr = wid >> 1, wc = wid & 1;
    int g = lane >> 4, c = lane & 15;
    int m0 = blockIdx.x * 128, n0 = blockIdx.y * 128;
    int srow = tid >> 3;
    int scol = (tid & 7) * 8;
    f32x4 acc[4][4] = {};
    for (int k0 = 0; k0 < K; k0 += 64) {
        __syncthreads();
#pragma unroll
        for (int p = 0; p < 4; p++) {
            int r = p * 32 + srow;
            *(int4*)&As[r][scol] = *(const int4*)(A + (size_t)(m0 + r) * K + k0 + scol);
            *(int4*)&Bs[r][scol] = *(const int4*)(B + (size_t)(n0 + r) * K + k0 + scol);
        }
        __syncthreads();
#pragma unroll
        for (int kk = 0; kk < 2; kk++) {
            short8t af[4], bf[4];
#pragma unroll
            for (int i = 0; i < 4; i++) {
                af[i] = *(const short8t*)&As[wr * 64 + i * 16 + c][kk * 32 + g * 8];
                bf[i] = *(const short8t*)&Bs[wc * 64 + i * 16 + c][kk * 32 + g * 8];
            }
#pragma unroll
            for (int i = 0; i < 4; i++)
#pragma unroll
                for (int j = 0; j < 4; j++)
                    acc[i][j] = __builtin_amdgcn_mfma_f32_16x16x32_bf16(
                        af[i], bf[j], acc[i][j], 0, 0, 0);
        }
    }
#pragma unroll
    for (int j = 0; j < 4; j++) {
        int n = n0 + wc * 64 + j * 16 + c;
        float bv = bias[n];
#pragma unroll
        for (int i = 0; i < 4; i++) {
#pragma unroll
            for (int r = 0; r < 4; r++) {
                int m = m0 + wr * 64 + i * 16 + g * 4 + r;
                C[(size_t)m * N + n] = scale * acc[i][j][r] + bv;
            }
        }
    }
}

// ---------------------------------------------------------------------------
// Rotate per-head 64-vectors, emit head-major bf16; optional rks = 0.125/|k|
__global__ void rot2_kernel(const float* __restrict__ in, int heads,
                            ushort* __restrict__ outb, float* __restrict__ rkso,
                            const float* __restrict__ ws) {
    int idx = blockIdx.x * 256 + threadIdx.x;
    if (idx >= MROWS * heads) return;
    int r = idx / heads;
    int hd = idx - r * heads;
    int tloc = r & (T_ - 1);
    int b = r >> 10;
    const float* p = in + (size_t)r * (heads * 64) + hd * 64;
    const float* b1 = ws + OFF_B1 + tloc * 32;
    const float* b2 = ws + OFF_B2 + tloc * 32;
    __align__(16) ushort ob[64];
    float nrm = 0.f;
#pragma unroll
    for (int i = 0; i < 8; i++) {
        float4 lo = *(const float4*)(p + i * 4);
        float4 hi = *(const float4*)(p + 32 + i * 4);
        float4 c1 = *(const float4*)(b1 + i * 4);
        float4 c2 = *(const float4*)(b2 + i * 4);
        float o1[4], o2[4];
        o1[0] = lo.x * c1.x - hi.x * c2.x;  o2[0] = lo.x * c2.x + hi.x * c1.x;
        o1[1] = lo.y * c1.y - hi.y * c2.y;  o2[1] = lo.y * c2.y + hi.y * c1.y;
        o1[2] = lo.z * c1.z - hi.z * c2.z;  o2[2] = lo.z * c2.z + hi.z * c1.z;
        o1[3] = lo.w * c1.w - hi.w * c2.w;  o2[3] = lo.w * c2.w + hi.w * c1.w;
#pragma unroll
        for (int j = 0; j < 4; j++) {
            ob[i * 4 + j]      = f2bf(o1[j]);
            ob[32 + i * 4 + j] = f2bf(o2[j]);
            nrm += o1[j] * o1[j] + o2[j] * o2[j];
        }
    }
    ushort* op = outb + ((size_t)(b * heads + hd) * T_ + tloc) * 64;
#pragma unroll
    for (int i = 0; i < 8; i++) *(int4*)(op + i * 8) = *(const int4*)&ob[i * 8];
    if (rkso) rkso[((b * heads + hd) << 10) + tloc] = ATTNSCALE_ / sqrtf(fmaxf(nrm, 1e-6f));
}

// ---------------------------------------------------------------------------
// Convert fp32 V [2048][768] -> head-major bf16 [b][12][1024][64]
__global__ void vconv_kernel(const float* __restrict__ V, ushort* __restrict__ Vb) {
    int idx = blockIdx.x * 256 + threadIdx.x;
    int base = idx * 4;
    int row = base / 768, col = base - row * 768;
    int b = row >> 10, t = row & (T_ - 1);
    int hk = col >> 6, d = col & 63;
    float4 v = *(const float4*)(V + (size_t)row * 768 + col);
    ushort4 o;
    o.x = f2bf(v.x); o.y = f2bf(v.y); o.z = f2bf(v.z); o.w = f2bf(v.w);
    *(ushort4*)(Vb + ((size_t)((b * NH + hk) * T_ + t)) * 64 + d) = o;
}

// ---------------------------------------------------------------------------
// MFMA flash attention: block = 64 q-rows x one (b,h); fp32 ctx out (round-2)
__global__ __launch_bounds__(256) void attn_mfma(
    const ushort* __restrict__ Qb, const ushort* __restrict__ Kb,
    const ushort* __restrict__ Vb, const float* __restrict__ rks,
    const float* __restrict__ sinks, const float* __restrict__ vnull,
    float* __restrict__ ctx) {
    __shared__ __align__(16) ushort Ks[64][72];
    __shared__ __align__(16) ushort Vt[64][72];
    __shared__ __align__(16) ushort Ps[4][16][72];
    __shared__ float rk_s[64];
    int tid  = threadIdx.x;
    int lane = tid & 63;
    int wid  = tid >> 6;
    int qi = 15 - blockIdx.x;
    int bh = blockIdx.y;
    int b = bh / HT, h = bh - b * HT;
    int hk = h % NH;
    int qt0 = qi * 64;
    int g = lane >> 4;
    int c = lane & 15;

    const ushort* qrow = Qb + ((size_t)(b * HT + h) * T_ + qt0 + wid * 16 + c) * 64;
    short8t qa0 = *(const short8t*)(qrow + g * 8);
    short8t qa1 = *(const short8t*)(qrow + 32 + g * 8);

    f32x4 oacc[4] = {};
    float sumw[4] = {0.f, 0.f, 0.f, 0.f};

    const size_t kvbase = (size_t)(b * NH + hk) * T_;
    for (int st = 0; st <= qi; st++) {
        int s0 = st * 64;
        __syncthreads();
        {
            int r = tid >> 2, c0 = (tid & 3) * 16;
            const ushort* kp = Kb + (kvbase + s0 + r) * 64 + c0;
            *(int4*)&Ks[r][c0]     = *(const int4*)kp;
            *(int4*)&Ks[r][c0 + 8] = *(const int4*)(kp + 8);
            const ushort* vp = Vb + (kvbase + s0 + r) * 64 + c0;
            __align__(16) ushort vv[16];
            *(int4*)&vv[0] = *(const int4*)vp;
            *(int4*)&vv[8] = *(const int4*)(vp + 8);
#pragma unroll
            for (int j = 0; j < 16; j++) Vt[c0 + j][r] = vv[j];
            if (tid < 64) rk_s[tid] = rks[kvbase + (size_t)s0 + tid];
        }
        __syncthreads();

        f32x4 sfr[4];
#pragma unroll
        for (int f = 0; f < 4; f++) {
            f32x4 cacc = {0.f, 0.f, 0.f, 0.f};
            short8t kb0 = *(const short8t*)&Ks[f * 16 + c][g * 8];
            cacc = __builtin_amdgcn_mfma_f32_16x16x32_bf16(qa0, kb0, cacc, 0, 0, 0);
            short8t kb1 = *(const short8t*)&Ks[f * 16 + c][32 + g * 8];
            cacc = __builtin_amdgcn_mfma_f32_16x16x32_bf16(qa1, kb1, cacc, 0, 0, 0);
            sfr[f] = cacc;
        }

        bool diag = (st == qi);
#pragma unroll
        for (int f = 0; f < 4; f++) {
            int scol = f * 16 + c;
            float rkv = rk_s[scol];
#pragma unroll
            for (int r = 0; r < 4; r++) {
                int trow = g * 4 + r;
                float x = sfr[f][r] * rkv;
                float w = __logf(1.f + __expf(x));
                w = w * __builtin_amdgcn_rcpf(1.f + __expf(-SCALE_W * w));
                if (diag && scol > wid * 16 + trow) w = 0.f;
                sumw[r] += w;
                Ps[wid][trow][scol] = f2bf(w);
            }
        }

#pragma unroll
        for (int hf = 0; hf < 2; hf++) {
            short8t pa = *(const short8t*)&Ps[wid][c][hf * 32 + g * 8];
#pragma unroll
            for (int f = 0; f < 4; f++) {
                short8t vb = *(const short8t*)&Vt[f * 16 + c][hf * 32 + g * 8];
                oacc[f] = __builtin_amdgcn_mfma_f32_16x16x32_bf16(pa, vb, oacc[f], 0, 0, 0);
            }
        }
    }

#pragma unroll
    for (int m = 1; m < 16; m <<= 1) {
#pragma unroll
        for (int r = 0; r < 4; r++) sumw[r] += __shfl_xor(sumw[r], m, 64);
    }
    float skv = sinks[h];
    float alpha[4], ps[4];
#pragma unroll
    for (int r = 0; r < 4; r++) {
        alpha[r] = 1.0f / (sumw[r] + skv + 1e-6f);
        ps[r] = skv * alpha[r];
    }
    int nb = h / NH;
#pragma unroll
    for (int f = 0; f < 4; f++) {
        float vn = vnull[h * 64 + f * 16 + c];
#pragma unroll
        for (int r = 0; r < 4; r++) {
            int t = qt0 + wid * 16 + g * 4 + r;
            ctx[((size_t)((b * NBR + nb) * T_ + t)) * 768 + hk * 64 + f * 16 + c]
                = oacc[f][r] * alpha[r] + ps[r] * vn;
        }
    }
}

// ---------------------------------------------------------------------------
// Y[m,c] = 0.25 * sum_nb ( ctx[nb] @ Wo[nb] )[m,c] + 0.25*sum_nb bo[nb,c]
__global__ __launch_bounds__(256) void gemm_out(
    const float* __restrict__ ctx, const float* __restrict__ Wo,
    const float* __restrict__ bo, float* __restrict__ Y) {
    __shared__ float As[16][68];
    __shared__ float Bs[16][68];
    int tid = threadIdx.x;
    int m0 = blockIdx.x * 64, n0 = blockIdx.y * 64;
    int b = m0 >> 10; int t0 = m0 & 1023;
    int row = tid >> 2, col4 = (tid & 3) << 2;
    int rB = tid >> 4, cB = (tid & 15) << 2;
    int ty = tid >> 4, tx = tid & 15;
    float acc[4][4] = {};
    for (int nb = 0; nb < 4; nb++) {
        const float* Ab = ctx + ((size_t)((b * NBR + nb) * T_ + t0)) * 768;
        const float* Wb = Wo + (size_t)nb * 768 * 768;
        for (int k0 = 0; k0 < 768; k0 += 16) {
            float4 av = *(const float4*)(Ab + (size_t)row * 768 + k0 + col4);
            As[col4 + 0][row] = av.x; As[col4 + 1][row] = av.y;
            As[col4 + 2][row] = av.z; As[col4 + 3][row] = av.w;
            float4 wv = *(const float4*)(Wb + (size_t)(k0 + rB) * 768 + n0 + cB);
            *(float4*)&Bs[rB][cB] = wv;
            __syncthreads();
#pragma unroll
            for (int kk = 0; kk < 16; kk++) {
                float4 a = *(const float4*)&As[kk][ty << 2];
                float4 bb = *(const float4*)&Bs[kk][tx << 2];
                float af[4] = {a.x, a.y, a.z, a.w};
                float bf[4] = {bb.x, bb.y, bb.z, bb.w};
#pragma unroll
                for (int i = 0; i < 4; i++)
#pragma unroll
                    for (int j = 0; j < 4; j++) acc[i][j] += af[i] * bf[j];
            }
            __syncthreads();
        }
    }
#pragma unroll
    for (int j = 0; j < 4; j++) {
        int n = n0 + (tx << 2) + j;
        float bsum = 0.25f * (bo[n] + bo[768 + n] + bo[1536 + n] + bo[2304 + n]);
#pragma unroll
        for (int i = 0; i < 4; i++) {
            int m = m0 + (ty << 2) + i;
            Y[(size_t)m * 768 + n] = 0.25f * acc[i][j] + bsum;
        }
    }
}

// ---------------------------------------------------------------------------
extern "C" void kernel_launch(void* const* d_in, const int* in_sizes, int n_in,
                              void* d_out, int out_size, void* d_ws, size_t ws_size,
                              hipStream_t stream) {
    const float* X   = (const float*)d_in[0];
    const float* Wq  = (const float*)d_in[1];
    const float* bq  = (const float*)d_in[2];
    const float* Wk  = (const float*)d_in[3];
    const float* bk  = (const float*)d_in[4];
    const float* Wv  = (const float*)d_in[5];
    const float* bv  = (const float*)d_in[6];
    const float* Aw  = (const float*)d_in[7];
    const float* idb = (const float*)d_in[8];
    const float* sk  = (const float*)d_in[9];
    const float* vn  = (const float*)d_in[10];
    const float* Wo  = (const float*)d_in[11];
    const float* bo  = (const float*)d_in[12];
    float* ws = (float*)d_ws;
    float* Y  = (float*)d_out;

    hipLaunchKernelGGL(cheb_kernel, dim3(4), dim3(256), 0, stream, ws);
    hipLaunchKernelGGL(prep_wq, dim3(48, 3), dim3(256), 0, stream, Aw, idb, Wq, bq, ws);
    // bf16 conversions: X, Wk, Wv, EWq
    hipLaunchKernelGGL(conv_bf16, dim3(1536), dim3(256), 0, stream,
                       X, (ushort*)(ws + OFF_XB));
    hipLaunchKernelGGL(conv_bf16, dim3(576), dim3(256), 0, stream,
                       Wk, (ushort*)(ws + OFF_WKB));
    hipLaunchKernelGGL(conv_bf16, dim3(576), dim3(256), 0, stream,
                       Wv, (ushort*)(ws + OFF_WVB));
    hipLaunchKernelGGL(conv_bf16, dim3(2304), dim3(256), 0, stream,
                       ws + OFF_EWQ, (ushort*)(ws + OFF_EWQB));
    // MFMA projections (fp32 out) — THE one variable under test this round
    hipLaunchKernelGGL(gemm_bf16, dim3(16, 24), dim3(256), 0, stream,
                       (const ushort*)(ws + OFF_XB), (const ushort*)(ws + OFF_EWQB),
                       ws + OFF_EBQ, ws + OFF_QF, 3072, 768, 1.0f);
    hipLaunchKernelGGL(gemm_bf16, dim3(16, 6), dim3(256), 0, stream,
                       (const ushort*)(ws + OFF_XB), (const ushort*)(ws + OFF_WKB),
                       bk, ws + OFF_KF, 768, 768, 1.0f);
    hipLaunchKernelGGL(gemm_bf16, dim3(16, 6), dim3(256), 0, stream,
                       (const ushort*)(ws + OFF_XB), (const ushort*)(ws + OFF_WVB),
                       bv, ws + OFF_VF, 768, 768, 1.0f);
    // K: rotate -> bf16 head-major + rks (before QB overwrites KF/VF)
    hipLaunchKernelGGL(rot2_kernel, dim3(96), dim3(256), 0, stream,
                       ws + OFF_KF, NH, (ushort*)(ws + OFF_KB), ws + OFF_RKS, ws);
    // V: convert -> bf16 head-major
    hipLaunchKernelGGL(vconv_kernel, dim3(1536), dim3(256), 0, stream,
                       ws + OFF_VF, (ushort*)(ws + OFF_VB));
    // Q: rotate -> bf16 head-major (over dead fp32 K/V region)
    hipLaunchKernelGGL(rot2_kernel, dim3(384), dim3(256), 0, stream,
                       ws + OFF_QF, HT, (ushort*)(ws + OFF_QB), (float*)nullptr, ws);
    // MFMA flash attention -> fp32 ctx (over dead fp32 Q region)
    hipLaunchKernelGGL(attn_mfma, dim3(16, 96), dim3(256), 0, stream,
                       (const ushort*)(ws + OFF_QB), (const ushort*)(ws + OFF_KB),
                       (const ushort*)(ws + OFF_VB), ws + OFF_RKS, sk, vn,
                       ws + OFF_CTX);
    // output projection + branch mean (round-2 fp32 VALU version)
    hipLaunchKernelGGL(gemm_out, dim3(32, 12), dim3(256), 0, stream,
                       ws + OFF_CTX, Wo, bo, Y);
}

// Round 5
// 371.149 us; speedup vs baseline: 3.9173x; 1.3216x over previous
//
#include <hip/hip_runtime.h>
#include <math.h>

#define B_ 2
#define T_ 1024
#define C_ 768
#define NH 12
#define NBR 4
#define DH_ 64
#define HT 48
#define MROWS (B_*T_)   // 2048

#define SCALE_W 1.8137993642342178f   // pi/sqrt(3)
#define ATTNSCALE_ 0.125f             // 64^-0.5

// ---------------- workspace layout (float offsets) -------------------------
// bf16 buffers reserve count/2 floats (audited after round-3 overlap bug)
#define OFF_B1    0
#define OFF_B2    (OFF_B1 + T_*32)            // 32768
#define OFF_EWQ   (OFF_B2 + T_*32)            // 65536    fp32[3072*768]
#define OFF_EBQ   (OFF_EWQ + 2359296)         // 2424832  fp32[3072]
#define OFF_XB    (OFF_EBQ + 3072)            // 2427904  ushort[2048*768]  -> 786432 fl
#define OFF_WKB   (OFF_XB + 786432)           // 3214336  ushort[768*768]   -> 294912 fl
#define OFF_WVB   (OFF_WKB + 294912)          // 3509248  ushort[768*768]   -> 294912 fl
#define OFF_EWQB  (OFF_WVB + 294912)          // 3804160  ushort[3072*768]  -> 1179648 fl
#define OFF_WOT   (OFF_EWQB + 1179648)        // 4983808  ushort[768*3072]  -> 1179648 fl
#define OFF_BSUM  (OFF_WOT + 1179648)         // 6163456  fp32[768]
#define OFF_QF    (OFF_BSUM + 768)            // 6164224  fp32[2048*3072] = 6291456 fl
#define OFF_KF    (OFF_QF + MROWS*3072)       // 12455680 fp32[2048*768] = 1572864 fl
#define OFF_VF    (OFF_KF + MROWS*768)        // 14028544 fp32[2048*768]
// bf16 Q aliases dead fp32 K+V (needs 3145728 fl = KF+VF exactly)
#define OFF_QB    OFF_KF
#define OFF_KB    (OFF_VF + MROWS*768)        // 15601408 ushort[2*12*1024*64] -> 786432 fl
#define OFF_VB    (OFF_KB + MROWS*384)        // 16387840
#define OFF_RKS   (OFF_VB + MROWS*384)        // 17174272 fp32[2*12*1024]
// bf16 ctx aliases dead fp32 Q: needs 3145728 fl, QF has 6291456 fl. fits.
#define OFF_CTXB  OFF_QF
// end = 17198848 floats = 68.8 MB (ws >= 72.7 MB proven in round 1)

typedef __attribute__((ext_vector_type(8))) short short8t;
typedef __attribute__((ext_vector_type(4))) float f32x4;

__device__ inline ushort f2bf(float f) {
    union { float f; unsigned u; } v; v.f = f;
    unsigned r = (v.u + 0x7FFFu + ((v.u >> 16) & 1u)) >> 16;
    return (ushort)r;
}

// ---------------------------------------------------------------------------
// Chebyshev rotation table: base1/base2[t][j], j=0..31, n_f[j]=2j+1 (exact)
__global__ void cheb_kernel(float* __restrict__ ws) {
    int t = blockIdx.x * 256 + threadIdx.x;
    if (t >= T_) return;
    float* b1 = ws + OFF_B1 + t * 32;
    float* b2 = ws + OFF_B2 + t * 32;
    float x = 2.0f * (float)t / 1023.0f - 1.0f;
    float Tp = 1.0f, Tc = x;
    for (int j = 0; j < 32; j++) {
        float r1 = Tc;
        float r2 = 2.0f * x * Tc - Tp;
        float nr = sqrtf(r1 * r1 + r2 * r2 + 1e-8f);
        b1[j] = r1 / nr;
        b2[j] = r2 / nr;
        Tp = r2;
        Tc = 2.0f * x * r2 - r1;
    }
}

// ---------------------------------------------------------------------------
// Fold M_h = I + (A - A^T) + diag(id_bias[h]) into Wq -> EWq (fp32), bq -> Ebq
__global__ __launch_bounds__(256) void prep_wq(
    const float* __restrict__ Aw, const float* __restrict__ idb,
    const float* __restrict__ Wq, const float* __restrict__ bq,
    float* __restrict__ ws) {
    __shared__ float Ms[64][64];
    int h = blockIdx.x;
    int tid = threadIdx.x;
    for (int i = tid; i < 4096; i += 256) {
        int d = i >> 6, e = i & 63;
        float v = Aw[d * 64 + e] - Aw[e * 64 + d];
        if (d == e) v += 1.0f + idb[h * 64 + d];
        Ms[d][e] = v;
    }
    __syncthreads();
    int c = blockIdx.y * 256 + tid;
    float wq[64];
#pragma unroll
    for (int d = 0; d < 64; d++) wq[d] = Wq[(size_t)(h * 64 + d) * 768 + c];
    float* EWq = ws + OFF_EWQ;
    for (int e = 0; e < 64; e++) {
        float acc = 0.f;
#pragma unroll
        for (int d = 0; d < 64; d++) acc += Ms[d][e] * wq[d];
        EWq[(size_t)(h * 64 + e) * 768 + c] = acc;
    }
    if (blockIdx.y == 0 && tid < 64) {
        int e = tid;
        float acc = 0.f;
        for (int d = 0; d < 64; d++) acc += Ms[d][e] * bq[h * 64 + d];
        ws[OFF_EBQ + h * 64 + e] = acc;
    }
}

// ---------------------------------------------------------------------------
// Elementwise fp32 -> bf16 (one float4 per thread)
__global__ void conv_bf16(const float* __restrict__ src, ushort* __restrict__ dst) {
    int i = (blockIdx.x * 256 + threadIdx.x) * 4;
    float4 v = *(const float4*)(src + i);
    ushort4 o;
    o.x = f2bf(v.x); o.y = f2bf(v.y); o.z = f2bf(v.z); o.w = f2bf(v.w);
    *(ushort4*)(dst + i) = o;
}

// ---------------------------------------------------------------------------
// WoT[c][nb*768+k] = bf16(Wo[nb][k][c])   grid (12,12,4)
__global__ __launch_bounds__(256) void woT_kernel(const float* __restrict__ Wo,
                                                  ushort* __restrict__ WoT) {
    __shared__ float tile[64][65];
    int nb = blockIdx.z;
    int k0 = blockIdx.x * 64, c0 = blockIdx.y * 64;
    int tx = threadIdx.x & 63, ty = threadIdx.x >> 6;
#pragma unroll
    for (int p = 0; p < 16; p++) {
        int ky = p * 4 + ty;
        tile[ky][tx] = Wo[((size_t)nb * 768 + k0 + ky) * 768 + c0 + tx];
    }
    __syncthreads();
#pragma unroll
    for (int p = 0; p < 16; p++) {
        int cy = p * 4 + ty;
        WoT[(size_t)(c0 + cy) * 3072 + nb * 768 + k0 + tx] = f2bf(tile[tx][cy]);
    }
}

// bsum[n] = 0.25 * sum_nb bo[nb][n]
__global__ void bias4_kernel(const float* __restrict__ bo, float* __restrict__ bsum) {
    int n = blockIdx.x * 256 + threadIdx.x;
    if (n < 768)
        bsum[n] = 0.25f * (bo[n] + bo[768 + n] + bo[1536 + n] + bo[2304 + n]);
}

// ---------------------------------------------------------------------------
// C[M,N] = scale*(A @ B^T) + bias   A[M][K],B[N][K] bf16, C fp32
// 128x128 tile, BK=64, 4 waves (2x2), each 64x64 via 4x4 16x16x32 fragments
__global__ __launch_bounds__(256) void gemm_bf16(
    const ushort* __restrict__ A, const ushort* __restrict__ B,
    const float* __restrict__ bias, float* __restrict__ C,
    int N, int K, float scale) {
    __shared__ __align__(16) ushort As[128][72];
    __shared__ __align__(16) ushort Bs[128][72];
    int tid = threadIdx.x;
    int lane = tid & 63, wid = tid >> 6;
    int wr = wid >> 1, wc = wid & 1;
    int g = lane >> 4, c = lane & 15;
    int m0 = blockIdx.x * 128, n0 = blockIdx.y * 128;
    int srow = tid >> 3;
    int scol = (tid & 7) * 8;
    f32x4 acc[4][4] = {};
    for (int k0 = 0; k0 < K; k0 += 64) {
        __syncthreads();
#pragma unroll
        for (int p = 0; p < 4; p++) {
            int r = p * 32 + srow;
            *(int4*)&As[r][scol] = *(const int4*)(A + (size_t)(m0 + r) * K + k0 + scol);
            *(int4*)&Bs[r][scol] = *(const int4*)(B + (size_t)(n0 + r) * K + k0 + scol);
        }
        __syncthreads();
#pragma unroll
        for (int kk = 0; kk < 2; kk++) {
            short8t af[4], bf[4];
#pragma unroll
            for (int i = 0; i < 4; i++) {
                af[i] = *(const short8t*)&As[wr * 64 + i * 16 + c][kk * 32 + g * 8];
                bf[i] = *(const short8t*)&Bs[wc * 64 + i * 16 + c][kk * 32 + g * 8];
            }
#pragma unroll
            for (int i = 0; i < 4; i++)
#pragma unroll
                for (int j = 0; j < 4; j++)
                    acc[i][j] = __builtin_amdgcn_mfma_f32_16x16x32_bf16(
                        af[i], bf[j], acc[i][j], 0, 0, 0);
        }
    }
#pragma unroll
    for (int j = 0; j < 4; j++) {
        int n = n0 + wc * 64 + j * 16 + c;
        float bv = bias[n];
#pragma unroll
        for (int i = 0; i < 4; i++) {
#pragma unroll
            for (int r = 0; r < 4; r++) {
                int m = m0 + wr * 64 + i * 16 + g * 4 + r;
                C[(size_t)m * N + n] = scale * acc[i][j][r] + bv;
            }
        }
    }
}

// ---------------------------------------------------------------------------
// Rotate per-head 64-vectors, emit head-major bf16; optional rks = 0.125/|k|
__global__ void rot2_kernel(const float* __restrict__ in, int heads,
                            ushort* __restrict__ outb, float* __restrict__ rkso,
                            const float* __restrict__ ws) {
    int idx = blockIdx.x * 256 + threadIdx.x;
    if (idx >= MROWS * heads) return;
    int r = idx / heads;
    int hd = idx - r * heads;
    int tloc = r & (T_ - 1);
    int b = r >> 10;
    const float* p = in + (size_t)r * (heads * 64) + hd * 64;
    const float* b1 = ws + OFF_B1 + tloc * 32;
    const float* b2 = ws + OFF_B2 + tloc * 32;
    __align__(16) ushort ob[64];
    float nrm = 0.f;
#pragma unroll
    for (int i = 0; i < 8; i++) {
        float4 lo = *(const float4*)(p + i * 4);
        float4 hi = *(const float4*)(p + 32 + i * 4);
        float4 c1 = *(const float4*)(b1 + i * 4);
        float4 c2 = *(const float4*)(b2 + i * 4);
        float o1[4], o2[4];
        o1[0] = lo.x * c1.x - hi.x * c2.x;  o2[0] = lo.x * c2.x + hi.x * c1.x;
        o1[1] = lo.y * c1.y - hi.y * c2.y;  o2[1] = lo.y * c2.y + hi.y * c1.y;
        o1[2] = lo.z * c1.z - hi.z * c2.z;  o2[2] = lo.z * c2.z + hi.z * c1.z;
        o1[3] = lo.w * c1.w - hi.w * c2.w;  o2[3] = lo.w * c2.w + hi.w * c1.w;
#pragma unroll
        for (int j = 0; j < 4; j++) {
            ob[i * 4 + j]      = f2bf(o1[j]);
            ob[32 + i * 4 + j] = f2bf(o2[j]);
            nrm += o1[j] * o1[j] + o2[j] * o2[j];
        }
    }
    ushort* op = outb + ((size_t)(b * heads + hd) * T_ + tloc) * 64;
#pragma unroll
    for (int i = 0; i < 8; i++) *(int4*)(op + i * 8) = *(const int4*)&ob[i * 8];
    if (rkso) rkso[((b * heads + hd) << 10) + tloc] = ATTNSCALE_ / sqrtf(fmaxf(nrm, 1e-6f));
}

// ---------------------------------------------------------------------------
// Convert fp32 V [2048][768] -> head-major bf16 [b][12][1024][64]
__global__ void vconv_kernel(const float* __restrict__ V, ushort* __restrict__ Vb) {
    int idx = blockIdx.x * 256 + threadIdx.x;
    int base = idx * 4;
    int row = base / 768, col = base - row * 768;
    int b = row >> 10, t = row & (T_ - 1);
    int hk = col >> 6, d = col & 63;
    float4 v = *(const float4*)(V + (size_t)row * 768 + col);
    ushort4 o;
    o.x = f2bf(v.x); o.y = f2bf(v.y); o.z = f2bf(v.z); o.w = f2bf(v.w);
    *(ushort4*)(Vb + ((size_t)((b * NH + hk) * T_ + t)) * 64 + d) = o;
}

// ---------------------------------------------------------------------------
// MFMA flash attention: block = 64 q-rows x one (b,h); writes bf16 ctx
// ctxb layout: [b*T+t][nb*768 + hk*64 + d]  (row-major 2048 x 3072)
__global__ __launch_bounds__(256) void attn_mfma(
    const ushort* __restrict__ Qb, const ushort* __restrict__ Kb,
    const ushort* __restrict__ Vb, const float* __restrict__ rks,
    const float* __restrict__ sinks, const float* __restrict__ vnull,
    ushort* __restrict__ ctxb) {
    __shared__ __align__(16) ushort Ks[64][72];
    __shared__ __align__(16) ushort Vt[64][72];
    __shared__ __align__(16) ushort Ps[4][16][72];
    __shared__ float rk_s[64];
    int tid  = threadIdx.x;
    int lane = tid & 63;
    int wid  = tid >> 6;
    int qi = 15 - blockIdx.x;
    int bh = blockIdx.y;
    int b = bh / HT, h = bh - b * HT;
    int hk = h % NH;
    int qt0 = qi * 64;
    int g = lane >> 4;
    int c = lane & 15;

    const ushort* qrow = Qb + ((size_t)(b * HT + h) * T_ + qt0 + wid * 16 + c) * 64;
    short8t qa0 = *(const short8t*)(qrow + g * 8);
    short8t qa1 = *(const short8t*)(qrow + 32 + g * 8);

    f32x4 oacc[4] = {};
    float sumw[4] = {0.f, 0.f, 0.f, 0.f};

    const size_t kvbase = (size_t)(b * NH + hk) * T_;
    for (int st = 0; st <= qi; st++) {
        int s0 = st * 64;
        __syncthreads();
        {
            int r = tid >> 2, c0 = (tid & 3) * 16;
            const ushort* kp = Kb + (kvbase + s0 + r) * 64 + c0;
            *(int4*)&Ks[r][c0]     = *(const int4*)kp;
            *(int4*)&Ks[r][c0 + 8] = *(const int4*)(kp + 8);
            const ushort* vp = Vb + (kvbase + s0 + r) * 64 + c0;
            __align__(16) ushort vv[16];
            *(int4*)&vv[0] = *(const int4*)vp;
            *(int4*)&vv[8] = *(const int4*)(vp + 8);
#pragma unroll
            for (int j = 0; j < 16; j++) Vt[c0 + j][r] = vv[j];
            if (tid < 64) rk_s[tid] = rks[kvbase + (size_t)s0 + tid];
        }
        __syncthreads();

        f32x4 sfr[4];
#pragma unroll
        for (int f = 0; f < 4; f++) {
            f32x4 cacc = {0.f, 0.f, 0.f, 0.f};
            short8t kb0 = *(const short8t*)&Ks[f * 16 + c][g * 8];
            cacc = __builtin_amdgcn_mfma_f32_16x16x32_bf16(qa0, kb0, cacc, 0, 0, 0);
            short8t kb1 = *(const short8t*)&Ks[f * 16 + c][32 + g * 8];
            cacc = __builtin_amdgcn_mfma_f32_16x16x32_bf16(qa1, kb1, cacc, 0, 0, 0);
            sfr[f] = cacc;
        }

        bool diag = (st == qi);
#pragma unroll
        for (int f = 0; f < 4; f++) {
            int scol = f * 16 + c;
            float rkv = rk_s[scol];
#pragma unroll
            for (int r = 0; r < 4; r++) {
                int trow = g * 4 + r;
                float x = sfr[f][r] * rkv;
                float w = __logf(1.f + __expf(x));
                w = w * __builtin_amdgcn_rcpf(1.f + __expf(-SCALE_W * w));
                if (diag && scol > wid * 16 + trow) w = 0.f;
                sumw[r] += w;
                Ps[wid][trow][scol] = f2bf(w);
            }
        }

#pragma unroll
        for (int hf = 0; hf < 2; hf++) {
            short8t pa = *(const short8t*)&Ps[wid][c][hf * 32 + g * 8];
#pragma unroll
            for (int f = 0; f < 4; f++) {
                short8t vb = *(const short8t*)&Vt[f * 16 + c][hf * 32 + g * 8];
                oacc[f] = __builtin_amdgcn_mfma_f32_16x16x32_bf16(pa, vb, oacc[f], 0, 0, 0);
            }
        }
    }

#pragma unroll
    for (int m = 1; m < 16; m <<= 1) {
#pragma unroll
        for (int r = 0; r < 4; r++) sumw[r] += __shfl_xor(sumw[r], m, 64);
    }
    float skv = sinks[h];
    float alpha[4], ps[4];
#pragma unroll
    for (int r = 0; r < 4; r++) {
        alpha[r] = 1.0f / (sumw[r] + skv + 1e-6f);
        ps[r] = skv * alpha[r];
    }
    int nb = h / NH;
#pragma unroll
    for (int f = 0; f < 4; f++) {
        float vn = vnull[h * 64 + f * 16 + c];
#pragma unroll
        for (int r = 0; r < 4; r++) {
            int t = qt0 + wid * 16 + g * 4 + r;
            ctxb[(size_t)(b * T_ + t) * 3072 + nb * 768 + hk * 64 + f * 16 + c]
                = f2bf(oacc[f][r] * alpha[r] + ps[r] * vn);
        }
    }
}

// ---------------------------------------------------------------------------
extern "C" void kernel_launch(void* const* d_in, const int* in_sizes, int n_in,
                              void* d_out, int out_size, void* d_ws, size_t ws_size,
                              hipStream_t stream) {
    const float* X   = (const float*)d_in[0];
    const float* Wq  = (const float*)d_in[1];
    const float* bq  = (const float*)d_in[2];
    const float* Wk  = (const float*)d_in[3];
    const float* bk  = (const float*)d_in[4];
    const float* Wv  = (const float*)d_in[5];
    const float* bv  = (const float*)d_in[6];
    const float* Aw  = (const float*)d_in[7];
    const float* idb = (const float*)d_in[8];
    const float* sk  = (const float*)d_in[9];
    const float* vn  = (const float*)d_in[10];
    const float* Wo  = (const float*)d_in[11];
    const float* bo  = (const float*)d_in[12];
    float* ws = (float*)d_ws;
    float* Y  = (float*)d_out;

    hipLaunchKernelGGL(cheb_kernel, dim3(4), dim3(256), 0, stream, ws);
    hipLaunchKernelGGL(prep_wq, dim3(48, 3), dim3(256), 0, stream, Aw, idb, Wq, bq, ws);
    // bf16 conversions: X, Wk, Wv, EWq
    hipLaunchKernelGGL(conv_bf16, dim3(1536), dim3(256), 0, stream,
                       X, (ushort*)(ws + OFF_XB));
    hipLaunchKernelGGL(conv_bf16, dim3(576), dim3(256), 0, stream,
                       Wk, (ushort*)(ws + OFF_WKB));
    hipLaunchKernelGGL(conv_bf16, dim3(576), dim3(256), 0, stream,
                       Wv, (ushort*)(ws + OFF_WVB));
    hipLaunchKernelGGL(conv_bf16, dim3(2304), dim3(256), 0, stream,
                       ws + OFF_EWQ, (ushort*)(ws + OFF_EWQB));
    // Wo -> transposed bf16 [768][3072]; branch-mean bias
    hipLaunchKernelGGL(woT_kernel, dim3(12, 12, 4), dim3(256), 0, stream,
                       Wo, (ushort*)(ws + OFF_WOT));
    hipLaunchKernelGGL(bias4_kernel, dim3(3), dim3(256), 0, stream, bo, ws + OFF_BSUM);
    // MFMA projections (fp32 out)
    hipLaunchKernelGGL(gemm_bf16, dim3(16, 24), dim3(256), 0, stream,
                       (const ushort*)(ws + OFF_XB), (const ushort*)(ws + OFF_EWQB),
                       ws + OFF_EBQ, ws + OFF_QF, 3072, 768, 1.0f);
    hipLaunchKernelGGL(gemm_bf16, dim3(16, 6), dim3(256), 0, stream,
                       (const ushort*)(ws + OFF_XB), (const ushort*)(ws + OFF_WKB),
                       bk, ws + OFF_KF, 768, 768, 1.0f);
    hipLaunchKernelGGL(gemm_bf16, dim3(16, 6), dim3(256), 0, stream,
                       (const ushort*)(ws + OFF_XB), (const ushort*)(ws + OFF_WVB),
                       bv, ws + OFF_VF, 768, 768, 1.0f);
    // K: rotate -> bf16 head-major + rks (before QB overwrites KF/VF)
    hipLaunchKernelGGL(rot2_kernel, dim3(96), dim3(256), 0, stream,
                       ws + OFF_KF, NH, (ushort*)(ws + OFF_KB), ws + OFF_RKS, ws);
    // V: convert -> bf16 head-major
    hipLaunchKernelGGL(vconv_kernel, dim3(1536), dim3(256), 0, stream,
                       ws + OFF_VF, (ushort*)(ws + OFF_VB));
    // Q: rotate -> bf16 head-major (over dead fp32 K/V region)
    hipLaunchKernelGGL(rot2_kernel, dim3(384), dim3(256), 0, stream,
                       ws + OFF_QF, HT, (ushort*)(ws + OFF_QB), (float*)nullptr, ws);
    // MFMA flash attention -> bf16 ctx (over dead fp32 Q region)
    hipLaunchKernelGGL(attn_mfma, dim3(16, 96), dim3(256), 0, stream,
                       (const ushort*)(ws + OFF_QB), (const ushort*)(ws + OFF_KB),
                       (const ushort*)(ws + OFF_VB), ws + OFF_RKS, sk, vn,
                       (ushort*)(ws + OFF_CTXB));
    // output projection: Y = 0.25 * ctxb @ WoT^T + bsum
    hipLaunchKernelGGL(gemm_bf16, dim3(16, 6), dim3(256), 0, stream,
                       (const ushort*)(ws + OFF_CTXB), (const ushort*)(ws + OFF_WOT),
                       ws + OFF_BSUM, Y, 768, 3072, 0.25f);
}

// Round 6
// 341.362 us; speedup vs baseline: 4.2591x; 1.0873x over previous
//
#include <hip/hip_runtime.h>
#include <math.h>

#define B_ 2
#define T_ 1024
#define C_ 768
#define NH 12
#define NBR 4
#define DH_ 64
#define HT 48
#define MROWS (B_*T_)   // 2048

#define SCALE_W 1.8137993642342178f   // pi/sqrt(3)
#define ATTNSCALE_ 0.125f             // 64^-0.5

// ---------------- workspace layout (float offsets, audited) ----------------
#define OFF_B1    0                          // fp32[1024*32]
#define OFF_B2    (OFF_B1 + 32768)           // 32768   fp32[1024*32]
#define OFF_QKVB  (OFF_B2 + 32768)           // 65536   fp32[4608]  (Ebq|bk|bv)
#define OFF_BSUM  (OFF_QKVB + 4608)          // 70144   fp32[768]
#define OFF_WQKV  (OFF_BSUM + 768)           // 70912   ushort[4608*768] -> 1769472 fl
#define OFF_XB    (OFF_WQKV + 1769472)       // 1840384 ushort[2048*768] -> 786432 fl
#define OFF_WOT   (OFF_XB + 786432)          // 2626816 ushort[768*3072] -> 1179648 fl
#define OFF_QF    (OFF_WOT + 1179648)        // 3806464 fp32[2048*3072] = 6291456 fl
#define OFF_KF    (OFF_QF + 6291456)         // 10097920 fp32[2048*768] = 1572864 fl
#define OFF_VF    (OFF_KF + 1572864)         // 11670784 fp32[2048*768]
// bf16 Q aliases dead fp32 KF+VF (needs 3145728 fl, KF+VF = 3145728 exactly)
#define OFF_QB    OFF_KF
#define OFF_KB    (OFF_VF + 1572864)         // 13243648 ushort[2*12*1024*64] -> 786432 fl
#define OFF_VB    (OFF_KB + 786432)          // 14030080 -> 786432 fl
#define OFF_RKS   (OFF_VB + 786432)          // 14816512 fp32[24576]
// bf16 ctx aliases dead fp32 QF (needs 3145728 fl of 6291456)
#define OFF_CTXB  OFF_QF
// end = 14841088 floats = 59.4 MB (72.7 MB proven available in round 1)

typedef __attribute__((ext_vector_type(8))) short short8t;
typedef __attribute__((ext_vector_type(4))) float f32x4;

__device__ inline ushort f2bf(float f) {
    union { float f; unsigned u; } v; v.f = f;
    unsigned r = (v.u + 0x7FFFu + ((v.u >> 16) & 1u)) >> 16;
    return (ushort)r;
}

// ---------------------------------------------------------------------------
__global__ void cheb_kernel(float* __restrict__ ws) {
    int t = blockIdx.x * 256 + threadIdx.x;
    if (t >= T_) return;
    float* b1 = ws + OFF_B1 + t * 32;
    float* b2 = ws + OFF_B2 + t * 32;
    float x = 2.0f * (float)t / 1023.0f - 1.0f;
    float Tp = 1.0f, Tc = x;
    for (int j = 0; j < 32; j++) {
        float r1 = Tc;
        float r2 = 2.0f * x * Tc - Tp;
        float nr = sqrtf(r1 * r1 + r2 * r2 + 1e-8f);
        b1[j] = r1 / nr;
        b2[j] = r2 / nr;
        Tp = r2;
        Tc = 2.0f * x * r2 - r1;
    }
}

// ---------------------------------------------------------------------------
// Fold M_h into Wq -> bf16 rows [0,3072) of WQKV; Ebq -> QKVB[0..3072)
__global__ __launch_bounds__(256) void prep_wq(
    const float* __restrict__ Aw, const float* __restrict__ idb,
    const float* __restrict__ Wq, const float* __restrict__ bq,
    float* __restrict__ ws) {
    __shared__ float Ms[64][64];
    int h = blockIdx.x;
    int tid = threadIdx.x;
    for (int i = tid; i < 4096; i += 256) {
        int d = i >> 6, e = i & 63;
        float v = Aw[d * 64 + e] - Aw[e * 64 + d];
        if (d == e) v += 1.0f + idb[h * 64 + d];
        Ms[d][e] = v;
    }
    __syncthreads();
    int c = blockIdx.y * 256 + tid;
    float wq[64];
#pragma unroll
    for (int d = 0; d < 64; d++) wq[d] = Wq[(size_t)(h * 64 + d) * 768 + c];
    ushort* EWqb = (ushort*)(ws + OFF_WQKV);
    for (int e = 0; e < 64; e++) {
        float acc = 0.f;
#pragma unroll
        for (int d = 0; d < 64; d++) acc += Ms[d][e] * wq[d];
        EWqb[(size_t)(h * 64 + e) * 768 + c] = f2bf(acc);
    }
    if (blockIdx.y == 0 && tid < 64) {
        int e = tid;
        float acc = 0.f;
        for (int d = 0; d < 64; d++) acc += Ms[d][e] * bq[h * 64 + d];
        ws[OFF_QKVB + h * 64 + e] = acc;
    }
}

// ---------------------------------------------------------------------------
__global__ void conv_bf16(const float* __restrict__ src, ushort* __restrict__ dst) {
    int i = (blockIdx.x * 256 + threadIdx.x) * 4;
    float4 v = *(const float4*)(src + i);
    ushort4 o;
    o.x = f2bf(v.x); o.y = f2bf(v.y); o.z = f2bf(v.z); o.w = f2bf(v.w);
    *(ushort4*)(dst + i) = o;
}

// ---------------------------------------------------------------------------
// WoT[c][nb*768+k] = bf16(Wo[nb][k][c])   grid (12,12,4)
__global__ __launch_bounds__(256) void woT_kernel(const float* __restrict__ Wo,
                                                  ushort* __restrict__ WoT) {
    __shared__ float tile[64][65];
    int nb = blockIdx.z;
    int k0 = blockIdx.x * 64, c0 = blockIdx.y * 64;
    int tx = threadIdx.x & 63, ty = threadIdx.x >> 6;
#pragma unroll
    for (int p = 0; p < 16; p++) {
        int ky = p * 4 + ty;
        tile[ky][tx] = Wo[((size_t)nb * 768 + k0 + ky) * 768 + c0 + tx];
    }
    __syncthreads();
#pragma unroll
    for (int p = 0; p < 16; p++) {
        int cy = p * 4 + ty;
        WoT[(size_t)(c0 + cy) * 3072 + nb * 768 + k0 + tx] = f2bf(tile[tx][cy]);
    }
}

// bsum + pack bk,bv into QKVB tail
__global__ void bias_prep(const float* __restrict__ bo, const float* __restrict__ bk,
                          const float* __restrict__ bv, float* __restrict__ ws) {
    int n = blockIdx.x * 256 + threadIdx.x;
    if (n < 768) {
        ws[OFF_BSUM + n] = 0.25f * (bo[n] + bo[768 + n] + bo[1536 + n] + bo[2304 + n]);
        ws[OFF_QKVB + 3072 + n] = bk[n];
        ws[OFF_QKVB + 3840 + n] = bv[n];
    }
}

// ---------------------------------------------------------------------------
// QKV gemm: [2048 x 4608] = XB @ WQKV^T + qkvbias, K=768; routed outputs.
// 128x128 tile, 4 waves (2x2), each 64x64 via 4x4 16x16x32 fragments
__global__ __launch_bounds__(256) void gemm_qkv(
    const ushort* __restrict__ A, const ushort* __restrict__ Bw,
    const float* __restrict__ qkvbias,
    float* __restrict__ Q, float* __restrict__ Kf, float* __restrict__ Vf) {
    __shared__ __align__(16) ushort As[128][72];
    __shared__ __align__(16) ushort Bs[128][72];
    const int K = 768;
    int tid = threadIdx.x;
    int lane = tid & 63, wid = tid >> 6;
    int wr = wid >> 1, wc = wid & 1;
    int g = lane >> 4, c = lane & 15;
    int m0 = blockIdx.x * 128, n0 = blockIdx.y * 128;
    int srow = tid >> 3;
    int scol = (tid & 7) * 8;
    f32x4 acc[4][4] = {};
    for (int k0 = 0; k0 < K; k0 += 64) {
        __syncthreads();
#pragma unroll
        for (int p = 0; p < 4; p++) {
            int r = p * 32 + srow;
            *(int4*)&As[r][scol] = *(const int4*)(A + (size_t)(m0 + r) * K + k0 + scol);
            *(int4*)&Bs[r][scol] = *(const int4*)(Bw + (size_t)(n0 + r) * K + k0 + scol);
        }
        __syncthreads();
#pragma unroll
        for (int kk = 0; kk < 2; kk++) {
            short8t af[4], bf[4];
#pragma unroll
            for (int i = 0; i < 4; i++) {
                af[i] = *(const short8t*)&As[wr * 64 + i * 16 + c][kk * 32 + g * 8];
                bf[i] = *(const short8t*)&Bs[wc * 64 + i * 16 + c][kk * 32 + g * 8];
            }
#pragma unroll
            for (int i = 0; i < 4; i++)
#pragma unroll
                for (int j = 0; j < 4; j++)
                    acc[i][j] = __builtin_amdgcn_mfma_f32_16x16x32_bf16(
                        af[i], bf[j], acc[i][j], 0, 0, 0);
        }
    }
    // output routing: y<24 -> Q(stride 3072), y<30 -> K, else V (stride 768)
    int y = blockIdx.y;
    float* outp; int nstr, nbase;
    if (y < 24)      { outp = Q;  nstr = 3072; nbase = 0; }
    else if (y < 30) { outp = Kf; nstr = 768;  nbase = 3072; }
    else             { outp = Vf; nstr = 768;  nbase = 3840; }
#pragma unroll
    for (int j = 0; j < 4; j++) {
        int n = n0 + wc * 64 + j * 16 + c;
        float bv = qkvbias[n];
#pragma unroll
        for (int i = 0; i < 4; i++) {
#pragma unroll
            for (int r = 0; r < 4; r++) {
                int m = m0 + wr * 64 + i * 16 + g * 4 + r;
                outp[(size_t)m * nstr + (n - nbase)] = acc[i][j][r] + bv;
            }
        }
    }
}

// ---------------------------------------------------------------------------
// Final gemm: Y[2048x768] = 0.25*(ctxb @ WoT^T) + bsum, K=3072.
// 64x64 tile, 4 waves (2x2), each 32x32 via 2x2 fragments. grid (32,12)
__global__ __launch_bounds__(256) void gemm_fin(
    const ushort* __restrict__ A, const ushort* __restrict__ Bw,
    const float* __restrict__ bsum, float* __restrict__ Y) {
    __shared__ __align__(16) ushort As[64][72];
    __shared__ __align__(16) ushort Bs[64][72];
    const int K = 3072;
    int tid = threadIdx.x;
    int lane = tid & 63, wid = tid >> 6;
    int wr = wid >> 1, wc = wid & 1;
    int g = lane >> 4, c = lane & 15;
    int m0 = blockIdx.x * 64, n0 = blockIdx.y * 64;
    int srow = tid >> 2;
    int scol = (tid & 3) * 16;
    f32x4 acc[2][2] = {};
    for (int k0 = 0; k0 < K; k0 += 64) {
        __syncthreads();
        *(int4*)&As[srow][scol]     = *(const int4*)(A + (size_t)(m0 + srow) * K + k0 + scol);
        *(int4*)&As[srow][scol + 8] = *(const int4*)(A + (size_t)(m0 + srow) * K + k0 + scol + 8);
        *(int4*)&Bs[srow][scol]     = *(const int4*)(Bw + (size_t)(n0 + srow) * K + k0 + scol);
        *(int4*)&Bs[srow][scol + 8] = *(const int4*)(Bw + (size_t)(n0 + srow) * K + k0 + scol + 8);
        __syncthreads();
#pragma unroll
        for (int kk = 0; kk < 2; kk++) {
            short8t af[2], bf[2];
#pragma unroll
            for (int i = 0; i < 2; i++) {
                af[i] = *(const short8t*)&As[wr * 32 + i * 16 + c][kk * 32 + g * 8];
                bf[i] = *(const short8t*)&Bs[wc * 32 + i * 16 + c][kk * 32 + g * 8];
            }
#pragma unroll
            for (int i = 0; i < 2; i++)
#pragma unroll
                for (int j = 0; j < 2; j++)
                    acc[i][j] = __builtin_amdgcn_mfma_f32_16x16x32_bf16(
                        af[i], bf[j], acc[i][j], 0, 0, 0);
        }
    }
#pragma unroll
    for (int j = 0; j < 2; j++) {
        int n = n0 + wc * 32 + j * 16 + c;
        float bv = bsum[n];
#pragma unroll
        for (int i = 0; i < 2; i++) {
#pragma unroll
            for (int r = 0; r < 4; r++) {
                int m = m0 + wr * 32 + i * 16 + g * 4 + r;
                Y[(size_t)m * 768 + n] = 0.25f * acc[i][j][r] + bv;
            }
        }
    }
}

// ---------------------------------------------------------------------------
// Rotate per-head 64-vectors, emit head-major bf16; optional rks = 0.125/|k|
__global__ void rot2_kernel(const float* __restrict__ in, int heads,
                            ushort* __restrict__ outb, float* __restrict__ rkso,
                            const float* __restrict__ ws) {
    int idx = blockIdx.x * 256 + threadIdx.x;
    if (idx >= MROWS * heads) return;
    int r = idx / heads;
    int hd = idx - r * heads;
    int tloc = r & (T_ - 1);
    int b = r >> 10;
    const float* p = in + (size_t)r * (heads * 64) + hd * 64;
    const float* b1 = ws + OFF_B1 + tloc * 32;
    const float* b2 = ws + OFF_B2 + tloc * 32;
    __align__(16) ushort ob[64];
    float nrm = 0.f;
#pragma unroll
    for (int i = 0; i < 8; i++) {
        float4 lo = *(const float4*)(p + i * 4);
        float4 hi = *(const float4*)(p + 32 + i * 4);
        float4 c1 = *(const float4*)(b1 + i * 4);
        float4 c2 = *(const float4*)(b2 + i * 4);
        float o1[4], o2[4];
        o1[0] = lo.x * c1.x - hi.x * c2.x;  o2[0] = lo.x * c2.x + hi.x * c1.x;
        o1[1] = lo.y * c1.y - hi.y * c2.y;  o2[1] = lo.y * c2.y + hi.y * c1.y;
        o1[2] = lo.z * c1.z - hi.z * c2.z;  o2[2] = lo.z * c2.z + hi.z * c1.z;
        o1[3] = lo.w * c1.w - hi.w * c2.w;  o2[3] = lo.w * c2.w + hi.w * c1.w;
#pragma unroll
        for (int j = 0; j < 4; j++) {
            ob[i * 4 + j]      = f2bf(o1[j]);
            ob[32 + i * 4 + j] = f2bf(o2[j]);
            nrm += o1[j] * o1[j] + o2[j] * o2[j];
        }
    }
    ushort* op = outb + ((size_t)(b * heads + hd) * T_ + tloc) * 64;
#pragma unroll
    for (int i = 0; i < 8; i++) *(int4*)(op + i * 8) = *(const int4*)&ob[i * 8];
    if (rkso) rkso[((b * heads + hd) << 10) + tloc] = ATTNSCALE_ / sqrtf(fmaxf(nrm, 1e-6f));
}

// ---------------------------------------------------------------------------
__global__ void vconv_kernel(const float* __restrict__ V, ushort* __restrict__ Vb) {
    int idx = blockIdx.x * 256 + threadIdx.x;
    int base = idx * 4;
    int row = base / 768, col = base - row * 768;
    int b = row >> 10, t = row & (T_ - 1);
    int hk = col >> 6, d = col & 63;
    float4 v = *(const float4*)(V + (size_t)row * 768 + col);
    ushort4 o;
    o.x = f2bf(v.x); o.y = f2bf(v.y); o.z = f2bf(v.z); o.w = f2bf(v.w);
    *(ushort4*)(Vb + ((size_t)((b * NH + hk) * T_ + t)) * 64 + d) = o;
}

// ---------------------------------------------------------------------------
// MFMA flash attention v2: block = 128 q-rows x one (b,h); 8 waves x 16 rows.
// Same fragment algebra as the verified round-5 kernel; global-index mask.
__global__ __launch_bounds__(512) void attn_mfma2(
    const ushort* __restrict__ Qb, const ushort* __restrict__ Kb,
    const ushort* __restrict__ Vb, const float* __restrict__ rks,
    const float* __restrict__ sinks, const float* __restrict__ vnull,
    ushort* __restrict__ ctxb) {
    __shared__ __align__(16) ushort Ks[64][72];
    __shared__ __align__(16) ushort Vt[64][72];
    __shared__ __align__(16) ushort Ps[8][16][72];
    __shared__ float rk_s[64];
    int tid  = threadIdx.x;
    int lane = tid & 63;
    int wid  = tid >> 6;              // 0..7
    int p = 7 - blockIdx.x;           // deepest q-blocks first
    int bh = blockIdx.y;
    int b = bh / HT, h = bh - b * HT;
    int hk = h % NH;
    int qt0 = p * 128;
    int g = lane >> 4;
    int c = lane & 15;
    int rowbase = qt0 + wid * 16;     // wave's first global q-row

    const ushort* qrow = Qb + ((size_t)(b * HT + h) * T_ + rowbase + c) * 64;
    short8t qa0 = *(const short8t*)(qrow + g * 8);
    short8t qa1 = *(const short8t*)(qrow + 32 + g * 8);

    f32x4 oacc[4] = {};
    float sumw[4] = {0.f, 0.f, 0.f, 0.f};

    const size_t kvbase = (size_t)(b * NH + hk) * T_;
    int nt = 2 * p + 2;
    int sr = tid >> 3;                // 0..63 staging row
    int sc = (tid & 7) * 8;           // 0..56 staging col
    for (int st = 0; st < nt; st++) {
        int s0 = st * 64;
        __syncthreads();
        {   // stage K tile + transposed V tile + rks (512 threads, 1 int4 each)
            *(int4*)&Ks[sr][sc] = *(const int4*)(Kb + (kvbase + s0 + sr) * 64 + sc);
            __align__(16) ushort vv[8];
            *(int4*)&vv[0] = *(const int4*)(Vb + (kvbase + s0 + sr) * 64 + sc);
#pragma unroll
            for (int j = 0; j < 8; j++) Vt[sc + j][sr] = vv[j];
            if (tid < 64) rk_s[tid] = rks[kvbase + (size_t)s0 + tid];
        }
        __syncthreads();

        if (s0 > rowbase + 15) continue;   // fully-masked for this wave

        f32x4 sfr[4];
#pragma unroll
        for (int f = 0; f < 4; f++) {
            f32x4 cacc = {0.f, 0.f, 0.f, 0.f};
            short8t kb0 = *(const short8t*)&Ks[f * 16 + c][g * 8];
            cacc = __builtin_amdgcn_mfma_f32_16x16x32_bf16(qa0, kb0, cacc, 0, 0, 0);
            short8t kb1 = *(const short8t*)&Ks[f * 16 + c][32 + g * 8];
            cacc = __builtin_amdgcn_mfma_f32_16x16x32_bf16(qa1, kb1, cacc, 0, 0, 0);
            sfr[f] = cacc;
        }

        bool diag = (s0 + 63 > rowbase);
#pragma unroll
        for (int f = 0; f < 4; f++) {
            int scol = f * 16 + c;
            float rkv = rk_s[scol];
#pragma unroll
            for (int r = 0; r < 4; r++) {
                int trow = g * 4 + r;
                float x = sfr[f][r] * rkv;
                float w = __logf(1.f + __expf(x));
                w = w * __builtin_amdgcn_rcpf(1.f + __expf(-SCALE_W * w));
                if (diag && s0 + scol > rowbase + trow) w = 0.f;
                sumw[r] += w;
                Ps[wid][trow][scol] = f2bf(w);
            }
        }

#pragma unroll
        for (int hf = 0; hf < 2; hf++) {
            short8t pa = *(const short8t*)&Ps[wid][c][hf * 32 + g * 8];
#pragma unroll
            for (int f = 0; f < 4; f++) {
                short8t vb = *(const short8t*)&Vt[f * 16 + c][hf * 32 + g * 8];
                oacc[f] = __builtin_amdgcn_mfma_f32_16x16x32_bf16(pa, vb, oacc[f], 0, 0, 0);
            }
        }
    }

#pragma unroll
    for (int m = 1; m < 16; m <<= 1) {
#pragma unroll
        for (int r = 0; r < 4; r++) sumw[r] += __shfl_xor(sumw[r], m, 64);
    }
    float skv = sinks[h];
    float alpha[4], ps[4];
#pragma unroll
    for (int r = 0; r < 4; r++) {
        alpha[r] = 1.0f / (sumw[r] + skv + 1e-6f);
        ps[r] = skv * alpha[r];
    }
    int nb = h / NH;
#pragma unroll
    for (int f = 0; f < 4; f++) {
        float vn = vnull[h * 64 + f * 16 + c];
#pragma unroll
        for (int r = 0; r < 4; r++) {
            int t = rowbase + g * 4 + r;
            ctxb[(size_t)(b * T_ + t) * 3072 + nb * 768 + hk * 64 + f * 16 + c]
                = f2bf(oacc[f][r] * alpha[r] + ps[r] * vn);
        }
    }
}

// ---------------------------------------------------------------------------
extern "C" void kernel_launch(void* const* d_in, const int* in_sizes, int n_in,
                              void* d_out, int out_size, void* d_ws, size_t ws_size,
                              hipStream_t stream) {
    const float* X   = (const float*)d_in[0];
    const float* Wq  = (const float*)d_in[1];
    const float* bq  = (const float*)d_in[2];
    const float* Wk  = (const float*)d_in[3];
    const float* bk  = (const float*)d_in[4];
    const float* Wv  = (const float*)d_in[5];
    const float* bv  = (const float*)d_in[6];
    const float* Aw  = (const float*)d_in[7];
    const float* idb = (const float*)d_in[8];
    const float* sk  = (const float*)d_in[9];
    const float* vn  = (const float*)d_in[10];
    const float* Wo  = (const float*)d_in[11];
    const float* bo  = (const float*)d_in[12];
    float* ws = (float*)d_ws;
    float* Y  = (float*)d_out;

    ushort* WQKV = (ushort*)(ws + OFF_WQKV);
    hipLaunchKernelGGL(cheb_kernel, dim3(4), dim3(256), 0, stream, ws);
    hipLaunchKernelGGL(prep_wq, dim3(48, 3), dim3(256), 0, stream, Aw, idb, Wq, bq, ws);
    // pack Wk, Wv (bf16) into WQKV rows [3072,3840) and [3840,4608)
    hipLaunchKernelGGL(conv_bf16, dim3(576), dim3(256), 0, stream,
                       Wk, WQKV + (size_t)3072 * 768);
    hipLaunchKernelGGL(conv_bf16, dim3(576), dim3(256), 0, stream,
                       Wv, WQKV + (size_t)3840 * 768);
    hipLaunchKernelGGL(conv_bf16, dim3(1536), dim3(256), 0, stream,
                       X, (ushort*)(ws + OFF_XB));
    hipLaunchKernelGGL(woT_kernel, dim3(12, 12, 4), dim3(256), 0, stream,
                       Wo, (ushort*)(ws + OFF_WOT));
    hipLaunchKernelGGL(bias_prep, dim3(3), dim3(256), 0, stream, bo, bk, bv, ws);
    // combined QKV projection (routed outputs)
    hipLaunchKernelGGL(gemm_qkv, dim3(16, 36), dim3(256), 0, stream,
                       (const ushort*)(ws + OFF_XB), WQKV, ws + OFF_QKVB,
                       ws + OFF_QF, ws + OFF_KF, ws + OFF_VF);
    // K: rotate -> bf16 head-major + rks (before QB overwrites KF/VF)
    hipLaunchKernelGGL(rot2_kernel, dim3(96), dim3(256), 0, stream,
                       ws + OFF_KF, NH, (ushort*)(ws + OFF_KB), ws + OFF_RKS, ws);
    hipLaunchKernelGGL(vconv_kernel, dim3(1536), dim3(256), 0, stream,
                       ws + OFF_VF, (ushort*)(ws + OFF_VB));
    // Q: rotate -> bf16 head-major (over dead fp32 K/V region)
    hipLaunchKernelGGL(rot2_kernel, dim3(384), dim3(256), 0, stream,
                       ws + OFF_QF, HT, (ushort*)(ws + OFF_QB), (float*)nullptr, ws);
    // MFMA flash attention v2 -> bf16 ctx (over dead fp32 Q region)
    hipLaunchKernelGGL(attn_mfma2, dim3(8, 96), dim3(512), 0, stream,
                       (const ushort*)(ws + OFF_QB), (const ushort*)(ws + OFF_KB),
                       (const ushort*)(ws + OFF_VB), ws + OFF_RKS, sk, vn,
                       (ushort*)(ws + OFF_CTXB));
    // output projection: Y = 0.25 * ctxb @ WoT^T + bsum
    hipLaunchKernelGGL(gemm_fin, dim3(32, 12), dim3(256), 0, stream,
                       (const ushort*)(ws + OFF_CTXB), (const ushort*)(ws + OFF_WOT),
                       ws + OFF_BSUM, Y);
}

// Round 7
// 328.431 us; speedup vs baseline: 4.4268x; 1.0394x over previous
//
#include <hip/hip_runtime.h>
#include <math.h>

#define B_ 2
#define T_ 1024
#define C_ 768
#define NH 12
#define NBR 4
#define DH_ 64
#define HT 48
#define MROWS (B_*T_)   // 2048

#define SCALE_W 1.8137993642342178f   // pi/sqrt(3)
#define ATTNSCALE_ 0.125f             // 64^-0.5

// ---------------- workspace layout (float offsets, audited) ----------------
#define OFF_B1    0                          // fp32[1024*32]
#define OFF_B2    (OFF_B1 + 32768)           // 32768   fp32[1024*32]
#define OFF_QKVB  (OFF_B2 + 32768)           // 65536   fp32[4608]  (Ebq|bk|bv)
#define OFF_BSUM  (OFF_QKVB + 4608)          // 70144   fp32[768]
#define OFF_WQKV  (OFF_BSUM + 768)           // 70912   ushort[4608*768] -> 1769472 fl
#define OFF_XB    (OFF_WQKV + 1769472)       // 1840384 ushort[2048*768] -> 786432 fl
#define OFF_WOT   (OFF_XB + 786432)          // 2626816 ushort[768*3072] -> 1179648 fl
#define OFF_QF    (OFF_WOT + 1179648)        // 3806464 fp32[2048*3072] = 6291456 fl
#define OFF_KF    (OFF_QF + 6291456)         // 10097920 fp32[2048*768] = 1572864 fl
#define OFF_VF    (OFF_KF + 1572864)         // 11670784 fp32[2048*768]
// bf16 Q aliases dead fp32 KF+VF (needs 3145728 fl, KF+VF = 3145728 exactly)
#define OFF_QB    OFF_KF
#define OFF_KB    (OFF_VF + 1572864)         // 13243648 ushort[2*12*1024*64] -> 786432 fl
#define OFF_VB    (OFF_KB + 786432)          // 14030080 -> 786432 fl
#define OFF_RKS   (OFF_VB + 786432)          // 14816512 fp32[24576]
// bf16 ctx aliases dead fp32 QF (needs 3145728 fl of 6291456)
#define OFF_CTXB  OFF_QF
// end = 14841088 floats = 59.4 MB

typedef __attribute__((ext_vector_type(8))) short short8t;
typedef __attribute__((ext_vector_type(4))) float f32x4;

__device__ inline ushort f2bf(float f) {
    union { float f; unsigned u; } v; v.f = f;
    unsigned r = (v.u + 0x7FFFu + ((v.u >> 16) & 1u)) >> 16;
    return (ushort)r;
}

typedef __attribute__((address_space(3))) void lds_vt;
typedef const __attribute__((address_space(1))) void gbl_vt;
static __device__ __forceinline__ void gload16(const void* g, void* l) {
    __builtin_amdgcn_global_load_lds((gbl_vt*)g, (lds_vt*)l, 16, 0, 0);
}

// ---------------------------------------------------------------------------
__global__ void cheb_kernel(float* __restrict__ ws) {
    int t = blockIdx.x * 256 + threadIdx.x;
    if (t >= T_) return;
    float* b1 = ws + OFF_B1 + t * 32;
    float* b2 = ws + OFF_B2 + t * 32;
    float x = 2.0f * (float)t / 1023.0f - 1.0f;
    float Tp = 1.0f, Tc = x;
    for (int j = 0; j < 32; j++) {
        float r1 = Tc;
        float r2 = 2.0f * x * Tc - Tp;
        float nr = sqrtf(r1 * r1 + r2 * r2 + 1e-8f);
        b1[j] = r1 / nr;
        b2[j] = r2 / nr;
        Tp = r2;
        Tc = 2.0f * x * r2 - r1;
    }
}

// ---------------------------------------------------------------------------
// Fold M_h into Wq -> bf16 rows [0,3072) of WQKV; Ebq -> QKVB[0..3072)
__global__ __launch_bounds__(256) void prep_wq(
    const float* __restrict__ Aw, const float* __restrict__ idb,
    const float* __restrict__ Wq, const float* __restrict__ bq,
    float* __restrict__ ws) {
    __shared__ float Ms[64][64];
    int h = blockIdx.x;
    int tid = threadIdx.x;
    for (int i = tid; i < 4096; i += 256) {
        int d = i >> 6, e = i & 63;
        float v = Aw[d * 64 + e] - Aw[e * 64 + d];
        if (d == e) v += 1.0f + idb[h * 64 + d];
        Ms[d][e] = v;
    }
    __syncthreads();
    int c = blockIdx.y * 256 + tid;
    float wq[64];
#pragma unroll
    for (int d = 0; d < 64; d++) wq[d] = Wq[(size_t)(h * 64 + d) * 768 + c];
    ushort* EWqb = (ushort*)(ws + OFF_WQKV);
    for (int e = 0; e < 64; e++) {
        float acc = 0.f;
#pragma unroll
        for (int d = 0; d < 64; d++) acc += Ms[d][e] * wq[d];
        EWqb[(size_t)(h * 64 + e) * 768 + c] = f2bf(acc);
    }
    if (blockIdx.y == 0 && tid < 64) {
        int e = tid;
        float acc = 0.f;
        for (int d = 0; d < 64; d++) acc += Ms[d][e] * bq[h * 64 + d];
        ws[OFF_QKVB + h * 64 + e] = acc;
    }
}

// ---------------------------------------------------------------------------
__global__ void conv_bf16(const float* __restrict__ src, ushort* __restrict__ dst) {
    int i = (blockIdx.x * 256 + threadIdx.x) * 4;
    float4 v = *(const float4*)(src + i);
    ushort4 o;
    o.x = f2bf(v.x); o.y = f2bf(v.y); o.z = f2bf(v.z); o.w = f2bf(v.w);
    *(ushort4*)(dst + i) = o;
}

// ---------------------------------------------------------------------------
// WoT[c][nb*768+k] = bf16(Wo[nb][k][c])   grid (12,12,4)
__global__ __launch_bounds__(256) void woT_kernel(const float* __restrict__ Wo,
                                                  ushort* __restrict__ WoT) {
    __shared__ float tile[64][65];
    int nb = blockIdx.z;
    int k0 = blockIdx.x * 64, c0 = blockIdx.y * 64;
    int tx = threadIdx.x & 63, ty = threadIdx.x >> 6;
#pragma unroll
    for (int p = 0; p < 16; p++) {
        int ky = p * 4 + ty;
        tile[ky][tx] = Wo[((size_t)nb * 768 + k0 + ky) * 768 + c0 + tx];
    }
    __syncthreads();
#pragma unroll
    for (int p = 0; p < 16; p++) {
        int cy = p * 4 + ty;
        WoT[(size_t)(c0 + cy) * 3072 + nb * 768 + k0 + tx] = f2bf(tile[tx][cy]);
    }
}

// bsum + pack bk,bv into QKVB tail
__global__ void bias_prep(const float* __restrict__ bo, const float* __restrict__ bk,
                          const float* __restrict__ bv, float* __restrict__ ws) {
    int n = blockIdx.x * 256 + threadIdx.x;
    if (n < 768) {
        ws[OFF_BSUM + n] = 0.25f * (bo[n] + bo[768 + n] + bo[1536 + n] + bo[2304 + n]);
        ws[OFF_QKVB + 3072 + n] = bk[n];
        ws[OFF_QKVB + 3840 + n] = bv[n];
    }
}

// Y pre-init with branch-mean bias (gemm_fin accumulates atomically on top)
__global__ void y_init(const float* __restrict__ bsum, float* __restrict__ Y) {
    int idx = (blockIdx.x * 256 + threadIdx.x) * 4;
    int n = idx - (idx / 768) * 768;
    float4 o = { bsum[n], bsum[n + 1], bsum[n + 2], bsum[n + 3] };
    *(float4*)(Y + idx) = o;
}

// ---------------------------------------------------------------------------
// Shared MFMA k-loop: 128x128 tile, BK=64, linear LDS [128][64] ushort with
// st-16x32-style XOR swizzle (byte ^= (row&7)<<4), staged via
// global_load_lds width=16 with inverse-swizzled per-lane global source.
static __device__ __forceinline__ void gemm_kloop128(
    const ushort* __restrict__ A, const ushort* __restrict__ B, int K,
    int m0, int n0, int k_begin, int k_end,
    ushort* AsU, ushort* BsU, f32x4 acc[4][4], int tid) {
    char* As = (char*)AsU;
    char* Bs = (char*)BsU;
    int lane = tid & 63, w = tid >> 6;
    int g = lane >> 4, c = lane & 15;
    int wr = w >> 1, wc = w & 1;
    // per-round staging coords (k-independent): dest p -> (row, unswizzled col)
    int srow[4], scol[4];
#pragma unroll
    for (int r = 0; r < 4; r++) {
        int p = r * 4096 + w * 1024 + lane * 16;
        int row = p >> 7;
        int bp = (p & 127) ^ ((row & 7) << 4);
        srow[r] = row;
        scol[r] = bp >> 1;
    }
    for (int k0 = k_begin; k0 < k_end; k0 += 64) {
        __syncthreads();
#pragma unroll
        for (int r = 0; r < 4; r++) {
            gload16(A + (size_t)(m0 + srow[r]) * K + k0 + scol[r],
                    As + r * 4096 + w * 1024);
            gload16(B + (size_t)(n0 + srow[r]) * K + k0 + scol[r],
                    Bs + r * 4096 + w * 1024);
        }
        __syncthreads();
#pragma unroll
        for (int kk = 0; kk < 2; kk++) {
            short8t af[4], bf[4];
#pragma unroll
            for (int i = 0; i < 4; i++) {
                int ra = wr * 64 + i * 16 + c;
                af[i] = *(const short8t*)(As + ra * 128 + ((kk * 64 + g * 16) ^ ((ra & 7) << 4)));
                int rb = wc * 64 + i * 16 + c;
                bf[i] = *(const short8t*)(Bs + rb * 128 + ((kk * 64 + g * 16) ^ ((rb & 7) << 4)));
            }
#pragma unroll
            for (int i = 0; i < 4; i++)
#pragma unroll
                for (int j = 0; j < 4; j++)
                    acc[i][j] = __builtin_amdgcn_mfma_f32_16x16x32_bf16(
                        af[i], bf[j], acc[i][j], 0, 0, 0);
        }
    }
}

// ---------------------------------------------------------------------------
// QKV gemm: [2048 x 4608] = XB @ WQKV^T + qkvbias, K=768; routed outputs.
__global__ __launch_bounds__(256) void gemm_qkv(
    const ushort* __restrict__ A, const ushort* __restrict__ Bw,
    const float* __restrict__ qkvbias,
    float* __restrict__ Q, float* __restrict__ Kf, float* __restrict__ Vf) {
    __shared__ __align__(16) ushort AsU[8192];
    __shared__ __align__(16) ushort BsU[8192];
    int tid = threadIdx.x;
    int lane = tid & 63, wid = tid >> 6;
    int wr = wid >> 1, wc = wid & 1;
    int g = lane >> 4, c = lane & 15;
    int m0 = blockIdx.x * 128, n0 = blockIdx.y * 128;
    f32x4 acc[4][4] = {};
    gemm_kloop128(A, Bw, 768, m0, n0, 0, 768, AsU, BsU, acc, tid);
    // output routing: y<24 -> Q(stride 3072), y<30 -> K, else V (stride 768)
    int y = blockIdx.y;
    float* outp; int nstr, nbase;
    if (y < 24)      { outp = Q;  nstr = 3072; nbase = 0; }
    else if (y < 30) { outp = Kf; nstr = 768;  nbase = 3072; }
    else             { outp = Vf; nstr = 768;  nbase = 3840; }
#pragma unroll
    for (int j = 0; j < 4; j++) {
        int n = n0 + wc * 64 + j * 16 + c;
        float bv = qkvbias[n];
#pragma unroll
        for (int i = 0; i < 4; i++) {
#pragma unroll
            for (int r = 0; r < 4; r++) {
                int m = m0 + wr * 64 + i * 16 + g * 4 + r;
                outp[(size_t)m * nstr + (n - nbase)] = acc[i][j][r] + bv;
            }
        }
    }
}

// ---------------------------------------------------------------------------
// Final gemm: Y += 0.25*(ctxb @ WoT^T), K=3072 split 3 ways. grid (16,6,3)
__global__ __launch_bounds__(256) void gemm_fin(
    const ushort* __restrict__ A, const ushort* __restrict__ Bw,
    float* __restrict__ Y) {
    __shared__ __align__(16) ushort AsU[8192];
    __shared__ __align__(16) ushort BsU[8192];
    int tid = threadIdx.x;
    int lane = tid & 63, wid = tid >> 6;
    int wr = wid >> 1, wc = wid & 1;
    int g = lane >> 4, c = lane & 15;
    int m0 = blockIdx.x * 128, n0 = blockIdx.y * 128;
    int kz = blockIdx.z * 1024;
    f32x4 acc[4][4] = {};
    gemm_kloop128(A, Bw, 3072, m0, n0, kz, kz + 1024, AsU, BsU, acc, tid);
#pragma unroll
    for (int j = 0; j < 4; j++) {
        int n = n0 + wc * 64 + j * 16 + c;
#pragma unroll
        for (int i = 0; i < 4; i++) {
#pragma unroll
            for (int r = 0; r < 4; r++) {
                int m = m0 + wr * 64 + i * 16 + g * 4 + r;
                atomicAdd(&Y[(size_t)m * 768 + n], 0.25f * acc[i][j][r]);
            }
        }
    }
}

// ---------------------------------------------------------------------------
// Rotate per-head 64-vectors, emit head-major bf16; optional rks = 0.125/|k|
__global__ void rot2_kernel(const float* __restrict__ in, int heads,
                            ushort* __restrict__ outb, float* __restrict__ rkso,
                            const float* __restrict__ ws) {
    int idx = blockIdx.x * 256 + threadIdx.x;
    if (idx >= MROWS * heads) return;
    int r = idx / heads;
    int hd = idx - r * heads;
    int tloc = r & (T_ - 1);
    int b = r >> 10;
    const float* p = in + (size_t)r * (heads * 64) + hd * 64;
    const float* b1 = ws + OFF_B1 + tloc * 32;
    const float* b2 = ws + OFF_B2 + tloc * 32;
    __align__(16) ushort ob[64];
    float nrm = 0.f;
#pragma unroll
    for (int i = 0; i < 8; i++) {
        float4 lo = *(const float4*)(p + i * 4);
        float4 hi = *(const float4*)(p + 32 + i * 4);
        float4 c1 = *(const float4*)(b1 + i * 4);
        float4 c2 = *(const float4*)(b2 + i * 4);
        float o1[4], o2[4];
        o1[0] = lo.x * c1.x - hi.x * c2.x;  o2[0] = lo.x * c2.x + hi.x * c1.x;
        o1[1] = lo.y * c1.y - hi.y * c2.y;  o2[1] = lo.y * c2.y + hi.y * c1.y;
        o1[2] = lo.z * c1.z - hi.z * c2.z;  o2[2] = lo.z * c2.z + hi.z * c1.z;
        o1[3] = lo.w * c1.w - hi.w * c2.w;  o2[3] = lo.w * c2.w + hi.w * c1.w;
#pragma unroll
        for (int j = 0; j < 4; j++) {
            ob[i * 4 + j]      = f2bf(o1[j]);
            ob[32 + i * 4 + j] = f2bf(o2[j]);
            nrm += o1[j] * o1[j] + o2[j] * o2[j];
        }
    }
    ushort* op = outb + ((size_t)(b * heads + hd) * T_ + tloc) * 64;
#pragma unroll
    for (int i = 0; i < 8; i++) *(int4*)(op + i * 8) = *(const int4*)&ob[i * 8];
    if (rkso) rkso[((b * heads + hd) << 10) + tloc] = ATTNSCALE_ / sqrtf(fmaxf(nrm, 1e-6f));
}

// ---------------------------------------------------------------------------
__global__ void vconv_kernel(const float* __restrict__ V, ushort* __restrict__ Vb) {
    int idx = blockIdx.x * 256 + threadIdx.x;
    int base = idx * 4;
    int row = base / 768, col = base - row * 768;
    int b = row >> 10, t = row & (T_ - 1);
    int hk = col >> 6, d = col & 63;
    float4 v = *(const float4*)(V + (size_t)row * 768 + col);
    ushort4 o;
    o.x = f2bf(v.x); o.y = f2bf(v.y); o.z = f2bf(v.z); o.w = f2bf(v.w);
    *(ushort4*)(Vb + ((size_t)((b * NH + hk) * T_ + t)) * 64 + d) = o;
}

// ---------------------------------------------------------------------------
// MFMA flash attention v2: block = 128 q-rows x one (b,h); 8 waves x 16 rows.
__global__ __launch_bounds__(512) void attn_mfma2(
    const ushort* __restrict__ Qb, const ushort* __restrict__ Kb,
    const ushort* __restrict__ Vb, const float* __restrict__ rks,
    const float* __restrict__ sinks, const float* __restrict__ vnull,
    ushort* __restrict__ ctxb) {
    __shared__ __align__(16) ushort Ks[64][72];
    __shared__ __align__(16) ushort Vt[64][72];
    __shared__ __align__(16) ushort Ps[8][16][72];
    __shared__ float rk_s[64];
    int tid  = threadIdx.x;
    int lane = tid & 63;
    int wid  = tid >> 6;              // 0..7
    int p = 7 - blockIdx.x;           // deepest q-blocks first
    int bh = blockIdx.y;
    int b = bh / HT, h = bh - b * HT;
    int hk = h % NH;
    int qt0 = p * 128;
    int g = lane >> 4;
    int c = lane & 15;
    int rowbase = qt0 + wid * 16;     // wave's first global q-row

    const ushort* qrow = Qb + ((size_t)(b * HT + h) * T_ + rowbase + c) * 64;
    short8t qa0 = *(const short8t*)(qrow + g * 8);
    short8t qa1 = *(const short8t*)(qrow + 32 + g * 8);

    f32x4 oacc[4] = {};
    float sumw[4] = {0.f, 0.f, 0.f, 0.f};

    const size_t kvbase = (size_t)(b * NH + hk) * T_;
    int nt = 2 * p + 2;
    int sr = tid >> 3;                // 0..63 staging row
    int sc = (tid & 7) * 8;           // 0..56 staging col
    for (int st = 0; st < nt; st++) {
        int s0 = st * 64;
        __syncthreads();
        {   // stage K tile + transposed V tile + rks
            *(int4*)&Ks[sr][sc] = *(const int4*)(Kb + (kvbase + s0 + sr) * 64 + sc);
            __align__(16) ushort vv[8];
            *(int4*)&vv[0] = *(const int4*)(Vb + (kvbase + s0 + sr) * 64 + sc);
#pragma unroll
            for (int j = 0; j < 8; j++) Vt[sc + j][sr] = vv[j];
            if (tid < 64) rk_s[tid] = rks[kvbase + (size_t)s0 + tid];
        }
        __syncthreads();

        if (s0 > rowbase + 15) continue;   // fully-masked for this wave

        f32x4 sfr[4];
#pragma unroll
        for (int f = 0; f < 4; f++) {
            f32x4 cacc = {0.f, 0.f, 0.f, 0.f};
            short8t kb0 = *(const short8t*)&Ks[f * 16 + c][g * 8];
            cacc = __builtin_amdgcn_mfma_f32_16x16x32_bf16(qa0, kb0, cacc, 0, 0, 0);
            short8t kb1 = *(const short8t*)&Ks[f * 16 + c][32 + g * 8];
            cacc = __builtin_amdgcn_mfma_f32_16x16x32_bf16(qa1, kb1, cacc, 0, 0, 0);
            sfr[f] = cacc;
        }

        bool diag = (s0 + 63 > rowbase);
#pragma unroll
        for (int f = 0; f < 4; f++) {
            int scol = f * 16 + c;
            float rkv = rk_s[scol];
#pragma unroll
            for (int r = 0; r < 4; r++) {
                int trow = g * 4 + r;
                float x = sfr[f][r] * rkv;
                float w = __logf(1.f + __expf(x));
                w = w * __builtin_amdgcn_rcpf(1.f + __expf(-SCALE_W * w));
                if (diag && s0 + scol > rowbase + trow) w = 0.f;
                sumw[r] += w;
                Ps[wid][trow][scol] = f2bf(w);
            }
        }

#pragma unroll
        for (int hf = 0; hf < 2; hf++) {
            short8t pa = *(const short8t*)&Ps[wid][c][hf * 32 + g * 8];
#pragma unroll
            for (int f = 0; f < 4; f++) {
                short8t vb = *(const short8t*)&Vt[f * 16 + c][hf * 32 + g * 8];
                oacc[f] = __builtin_amdgcn_mfma_f32_16x16x32_bf16(pa, vb, oacc[f], 0, 0, 0);
            }
        }
    }

#pragma unroll
    for (int m = 1; m < 16; m <<= 1) {
#pragma unroll
        for (int r = 0; r < 4; r++) sumw[r] += __shfl_xor(sumw[r], m, 64);
    }
    float skv = sinks[h];
    float alpha[4], ps[4];
#pragma unroll
    for (int r = 0; r < 4; r++) {
        alpha[r] = 1.0f / (sumw[r] + skv + 1e-6f);
        ps[r] = skv * alpha[r];
    }
    int nb = h / NH;
#pragma unroll
    for (int f = 0; f < 4; f++) {
        float vn = vnull[h * 64 + f * 16 + c];
#pragma unroll
        for (int r = 0; r < 4; r++) {
            int t = rowbase + g * 4 + r;
            ctxb[(size_t)(b * T_ + t) * 3072 + nb * 768 + hk * 64 + f * 16 + c]
                = f2bf(oacc[f][r] * alpha[r] + ps[r] * vn);
        }
    }
}

// ---------------------------------------------------------------------------
extern "C" void kernel_launch(void* const* d_in, const int* in_sizes, int n_in,
                              void* d_out, int out_size, void* d_ws, size_t ws_size,
                              hipStream_t stream) {
    const float* X   = (const float*)d_in[0];
    const float* Wq  = (const float*)d_in[1];
    const float* bq  = (const float*)d_in[2];
    const float* Wk  = (const float*)d_in[3];
    const float* bk  = (const float*)d_in[4];
    const float* Wv  = (const float*)d_in[5];
    const float* bv  = (const float*)d_in[6];
    const float* Aw  = (const float*)d_in[7];
    const float* idb = (const float*)d_in[8];
    const float* sk  = (const float*)d_in[9];
    const float* vn  = (const float*)d_in[10];
    const float* Wo  = (const float*)d_in[11];
    const float* bo  = (const float*)d_in[12];
    float* ws = (float*)d_ws;
    float* Y  = (float*)d_out;

    ushort* WQKV = (ushort*)(ws + OFF_WQKV);
    hipLaunchKernelGGL(cheb_kernel, dim3(4), dim3(256), 0, stream, ws);
    hipLaunchKernelGGL(prep_wq, dim3(48, 3), dim3(256), 0, stream, Aw, idb, Wq, bq, ws);
    hipLaunchKernelGGL(conv_bf16, dim3(576), dim3(256), 0, stream,
                       Wk, WQKV + (size_t)3072 * 768);
    hipLaunchKernelGGL(conv_bf16, dim3(576), dim3(256), 0, stream,
                       Wv, WQKV + (size_t)3840 * 768);
    hipLaunchKernelGGL(conv_bf16, dim3(1536), dim3(256), 0, stream,
                       X, (ushort*)(ws + OFF_XB));
    hipLaunchKernelGGL(woT_kernel, dim3(12, 12, 4), dim3(256), 0, stream,
                       Wo, (ushort*)(ws + OFF_WOT));
    hipLaunchKernelGGL(bias_prep, dim3(3), dim3(256), 0, stream, bo, bk, bv, ws);
    // combined QKV projection (gl_lds + swizzle)
    hipLaunchKernelGGL(gemm_qkv, dim3(16, 36), dim3(256), 0, stream,
                       (const ushort*)(ws + OFF_XB), WQKV, ws + OFF_QKVB,
                       ws + OFF_QF, ws + OFF_KF, ws + OFF_VF);
    hipLaunchKernelGGL(rot2_kernel, dim3(96), dim3(256), 0, stream,
                       ws + OFF_KF, NH, (ushort*)(ws + OFF_KB), ws + OFF_RKS, ws);
    hipLaunchKernelGGL(vconv_kernel, dim3(1536), dim3(256), 0, stream,
                       ws + OFF_VF, (ushort*)(ws + OFF_VB));
    hipLaunchKernelGGL(rot2_kernel, dim3(384), dim3(256), 0, stream,
                       ws + OFF_QF, HT, (ushort*)(ws + OFF_QB), (float*)nullptr, ws);
    hipLaunchKernelGGL(attn_mfma2, dim3(8, 96), dim3(512), 0, stream,
                       (const ushort*)(ws + OFF_QB), (const ushort*)(ws + OFF_KB),
                       (const ushort*)(ws + OFF_VB), ws + OFF_RKS, sk, vn,
                       (ushort*)(ws + OFF_CTXB));
    // output projection: Y = bsum + 0.25 * ctxb @ WoT^T  (init + split-K atomic)
    hipLaunchKernelGGL(y_init, dim3(1536), dim3(256), 0, stream, ws + OFF_BSUM, Y);
    hipLaunchKernelGGL(gemm_fin, dim3(16, 6, 3), dim3(256), 0, stream,
                       (const ushort*)(ws + OFF_CTXB), (const ushort*)(ws + OFF_WOT), Y);
}